// Round 1
// baseline (292.139 us; speedup 1.0000x reference)
//
#include <hip/hip_runtime.h>
#include <stdint.h>

// SeqAttention: B=4,H=8,M=1024,L=3200,D=128,HID=1024, ATTN_LIM=2048, RAMP=128
#define B_   4
#define H_   8
#define BH_  32
#define M_   1024
#define L_   3200
#define D_   128
#define HID_ 1024
#define NT64 50                 /* L/64 */
#define CAUSAL_K 2175           /* max_mem - M - 1 */
#define POS_OFF  1152           /* L - 2M */
#define SCALE 0.08838834764831845f /* 1/sqrt(128) */
#define NEGV (-3.0e38f)
#define NEGH (-1.0e38f)

typedef short  bf16x8 __attribute__((ext_vector_type(8)));
typedef float  f32x4  __attribute__((ext_vector_type(4)));

__device__ __forceinline__ unsigned short f2bf(float x) {
    union { float f; uint32_t u; } v; v.f = x;
    return (unsigned short)((v.u + 0x7FFFu + ((v.u >> 16) & 1u)) >> 16);
}
__device__ __forceinline__ float bf2f(unsigned short h) {
    union { uint32_t u; float f; } v; v.u = ((uint32_t)h) << 16; return v.f;
}

// ---- remaining_offset[b,l] = sigmoid(dot(hid/16, w) + b)*2048 - counter ----
__global__ void span_kernel(const float* __restrict__ hid,
                            const float* __restrict__ counter,
                            const float* __restrict__ sw,
                            const float* __restrict__ sb,
                            float* __restrict__ r0_ws,
                            float* __restrict__ r0_out) {
    const int row  = blockIdx.x * 4 + (threadIdx.x >> 6);   // one wave per (b,l)
    const int lane = threadIdx.x & 63;
    const float* h = hid + (size_t)row * HID_;
    float acc = 0.f;
#pragma unroll
    for (int it = 0; it < 4; ++it) {
        const int k = it * 256 + lane * 4;
        const float4 a = *(const float4*)(h + k);
        const float4 w = *(const float4*)(sw + k);
        acc += a.x*w.x + a.y*w.y + a.z*w.z + a.w*w.w;
    }
#pragma unroll
    for (int off = 32; off; off >>= 1) acc += __shfl_down(acc, off);
    if (lane == 0) {
        const float x  = acc * (1.0f/16.0f) + sb[0];
        const float ms = 2048.0f / (1.0f + __expf(-x));
        const float r0 = ms - counter[row];
        r0_ws[row]  = r0;
        r0_out[row] = r0;
    }
}

// ---- per-(b, 64-wide l-tile) max of remaining_offset, for tile skipping ----
__global__ void tilemax_kernel(const float* __restrict__ r0_ws,
                               float* __restrict__ tmax) {
    const int t = blockIdx.x;            // flat tile over b*NT64
    const int lane = threadIdx.x;
    float v = r0_ws[t * 64 + lane];
#pragma unroll
    for (int off = 32; off; off >>= 1) v = fmaxf(v, __shfl_down(v, off));
    if (lane == 0) tmax[t] = v;
}

// ---- aux_loss[b] = sum_{l,m: -128 < r0-m < 0} (r0-m) /128/1024*1e-6 ----
__global__ void aux_kernel(const float* __restrict__ r0_ws,
                           float* __restrict__ aux_out) {
    const int b = blockIdx.x, tid = threadIdx.x;
    float s = 0.f;
    for (int l = tid; l < L_; l += 256) {
        const float r = r0_ws[b * L_ + l];
        int fl = (int)floorf(r);
        int m0 = fl < 0 ? 0 : fl;
        int m1 = fl + 128; if (m1 > M_ - 1) m1 = M_ - 1;
        for (int m = m0; m <= m1; ++m) {
            const float rs = r - (float)m;
            const float em = fminf(fmaxf(rs * 0.0078125f + 1.0f, 0.f), 1.f);
            if (em > 0.f && em < 1.f) s += rs;
        }
    }
    __shared__ float red[256];
    red[tid] = s; __syncthreads();
    for (int st = 128; st; st >>= 1) {
        if (tid < st) red[tid] += red[tid + st];
        __syncthreads();
    }
    if (tid == 0) aux_out[b] = red[0] * (1.0f/128.0f) * (1.0f/1024.0f) * 1e-6f;
}

// ---- flash attention with expire-span masking + skewed rel-pos bias ----
#define KS_STR 136   /* 128 + 8 pad (bf16 elems) */
#define VT_STR 72    /* 64 + 8 */
#define PE_STR 136
#define P_STR  72
#define T_STR  72

__global__ void __launch_bounds__(256, 2)
attn_kernel(const float* __restrict__ Q, const float* __restrict__ K,
            const float* __restrict__ V, const float* __restrict__ PE,
            const float* __restrict__ r0g, const float* __restrict__ tmax,
            float* __restrict__ out) {
    __shared__ short Ks[64 * KS_STR];        // K tile, row-major [l][d]
    __shared__ short Vt[128 * VT_STR];       // V tile transposed [d][l]
    __shared__ short PEP[64 * PE_STR];       // PE^T stage [c][d]  /  P tile [m][l]
    __shared__ short Tb[2][64 * T_STR];      // rolling Q@PE tiles [i][c]
    __shared__ float r0s[64];

    const int bh = blockIdx.y;
    const int b  = bh >> 3;
    const int i0 = blockIdx.x << 6;
    const int tid  = threadIdx.x;
    const int wave = tid >> 6;
    const int lane = tid & 63;
    const int lq   = lane & 15;
    const int quad = lane >> 4;

    // Q A-fragments for this wave's 16-row strip (registers, loaded once)
    bf16x8 qfrag[4];
    {
        const float* qp = Q + ((size_t)bh * M_ + (i0 + wave * 16 + lq)) * D_;
#pragma unroll
        for (int kk = 0; kk < 4; ++kk) {
            const float* p = qp + kk * 32 + quad * 8;
            bf16x8 f;
#pragma unroll
            for (int j = 0; j < 8; ++j) f[j] = (short)f2bf(p[j]);
            qfrag[kk] = f;
        }
    }

    f32x4 oacc[8];
#pragma unroll
    for (int d = 0; d < 8; ++d) oacc[d] = (f32x4){0.f, 0.f, 0.f, 0.f};
    float mrun[4] = {NEGV, NEGV, NEGV, NEGV};
    float Zr[4]   = {0.f, 0.f, 0.f, 0.f};
    float Zm[4]   = {0.f, 0.f, 0.f, 0.f};

    int tlo = 0, thi = 1;
    int prev_c0 = -100000;

    auto stagePE = [&](int cbase) {
#pragma unroll
        for (int it = 0; it < 8; ++it) {
            const int f4 = it * 256 + tid;
            const int d  = f4 >> 4;
            const int cl = (f4 & 15) << 2;
#pragma unroll
            for (int j = 0; j < 4; ++j) {
                const int cg = cbase + cl + j;
                const float v = (cg >= 0 && cg < M_) ? PE[d * M_ + cg] : 0.f;
                PEP[(cl + j) * PE_STR + d] = (short)f2bf(v);
            }
        }
    };
    auto computeT = [&](short* tb) {
#pragma unroll
        for (int nt = 0; nt < 4; ++nt) {
            f32x4 acc = (f32x4){0.f, 0.f, 0.f, 0.f};
#pragma unroll
            for (int kk = 0; kk < 4; ++kk) {
                const bf16x8 bf = *(const bf16x8*)&PEP[(nt*16 + lq) * PE_STR + kk*32 + quad*8];
                acc = __builtin_amdgcn_mfma_f32_16x16x32_bf16(qfrag[kk], bf, acc, 0, 0, 0);
            }
#pragma unroll
            for (int r = 0; r < 4; ++r)
                tb[(wave*16 + quad*4 + r) * T_STR + nt*16 + lq] = (short)f2bf(acc[r]);
        }
    };

    const int lt_end = min(NT64, (int)blockIdx.x + 35);   // causal: l0 <= i0+2238
    for (int lt = 0; lt < lt_end; ++lt) {
        const int l0 = lt << 6;
        // expire-span tile skip: live iff max(r0) > i0 - 128 (block-uniform)
        if (!(tmax[b * NT64 + lt] > (float)(i0 - 128))) continue;

        __syncthreads();   // previous iteration's LDS reads done
        // stage K (bf16 [l][d]) and V (bf16 transposed [d][l]), r0 slice
        {
            const float* kbase = K + ((size_t)bh * L_ + l0) * D_;
            const float* vbase = V + ((size_t)bh * L_ + l0) * D_;
#pragma unroll
            for (int it = 0; it < 8; ++it) {
                const int f4 = it * 256 + tid;
                const int row = f4 >> 5;
                const int ds  = (f4 & 31) << 2;
                const float4 kv = *(const float4*)(kbase + row * D_ + ds);
                uint2 pk;
                pk.x = (uint32_t)f2bf(kv.x) | ((uint32_t)f2bf(kv.y) << 16);
                pk.y = (uint32_t)f2bf(kv.z) | ((uint32_t)f2bf(kv.w) << 16);
                *(uint2*)&Ks[row * KS_STR + ds] = pk;
                const float4 vv = *(const float4*)(vbase + row * D_ + ds);
                Vt[(ds+0) * VT_STR + row] = (short)f2bf(vv.x);
                Vt[(ds+1) * VT_STR + row] = (short)f2bf(vv.y);
                Vt[(ds+2) * VT_STR + row] = (short)f2bf(vv.z);
                Vt[(ds+3) * VT_STR + row] = (short)f2bf(vv.w);
            }
            if (tid < 64) r0s[tid] = r0g[b * L_ + l0 + tid];
        }

        // rel-pos T tiles: window c in [c0-63, c0+63], two aligned 64-tiles
        const int c0 = l0 - i0 - POS_OFF;
        const bool need_pos = (c0 + 63 >= 0) && (c0 - 63 <= M_ - 1);
        if (need_pos) {
            if (prev_c0 == c0 - 64) {           // roll: old high tile becomes low
                const int t = tlo; tlo = thi; thi = t;
                stagePE(c0);
                __syncthreads();                // K/V + PE staged
                computeT(Tb[thi]);
            } else {
                stagePE(c0 - 64);
                __syncthreads();
                computeT(Tb[tlo]);
                __syncthreads();                // PEP reads done before overwrite
                stagePE(c0);
                __syncthreads();
                computeT(Tb[thi]);
            }
            prev_c0 = c0;
        } else {
            __syncthreads();                    // K/V staged
        }

        // S = Q @ K^T  (16x64 strip per wave)
        f32x4 sfrag[4];
#pragma unroll
        for (int nt = 0; nt < 4; ++nt) {
            f32x4 acc = (f32x4){0.f, 0.f, 0.f, 0.f};
#pragma unroll
            for (int kk = 0; kk < 4; ++kk) {
                const bf16x8 bf = *(const bf16x8*)&Ks[(nt*16 + lq) * KS_STR + kk*32 + quad*8];
                acc = __builtin_amdgcn_mfma_f32_16x16x32_bf16(qfrag[kk], bf, acc, 0, 0, 0);
            }
            sfrag[nt] = acc;
        }
        __syncthreads();   // T writes visible; PEP (PE) reads done before P writes

        // masked scores (C-layout: row = quad*4+r, col = lq + 16*nt)
        float sv[4][4];
#pragma unroll
        for (int r = 0; r < 4; ++r) {
            const int iq = i0 + wave*16 + quad*4 + r;
#pragma unroll
            for (int nt = 0; nt < 4; ++nt) {
                const int l = l0 + nt*16 + lq;
                float s = sfrag[nt][r];
                const int c = l - iq - POS_OFF;
                if (c >= 0 && c < M_) {
                    const int cb = c - (c0 - 64);          // in [1,127]
                    const short* tbp = (cb & 64) ? Tb[thi] : Tb[tlo];
                    s += bf2f((unsigned short)tbp[(wave*16 + quad*4 + r) * T_STR + (cb & 63)]);
                }
                const float em = fminf(fmaxf((r0s[nt*16 + lq] - (float)iq) * 0.0078125f + 1.0f, 0.f), 1.f);
                const bool live = (l <= iq + CAUSAL_K) && (em > 0.f);
                sv[r][nt] = live ? s * SCALE : NEGV;
            }
        }

        // online softmax update + P (= e * emask) to LDS
#pragma unroll
        for (int r = 0; r < 4; ++r) {
            float v = fmaxf(fmaxf(sv[r][0], sv[r][1]), fmaxf(sv[r][2], sv[r][3]));
#pragma unroll
            for (int off = 1; off < 16; off <<= 1) v = fmaxf(v, __shfl_xor(v, off));
            const float nm = fmaxf(mrun[r], v);
            float alpha, pmv[4];
            float psum = 0.f, pmsum = 0.f;
            if (nm > NEGH) {
                alpha = (mrun[r] > NEGH) ? __expf(mrun[r] - nm) : 0.f;
                const int iq = i0 + wave*16 + quad*4 + r;
#pragma unroll
                for (int nt = 0; nt < 4; ++nt) {
                    const float p = __expf(sv[r][nt] - nm);   // dead -> underflow 0
                    const float em = fminf(fmaxf((r0s[nt*16 + lq] - (float)iq) * 0.0078125f + 1.0f, 0.f), 1.f);
                    const float pm = p * em;
                    psum += p; pmsum += pm; pmv[nt] = pm;
                }
            } else {
                alpha = 1.f;
                pmv[0] = pmv[1] = pmv[2] = pmv[3] = 0.f;
            }
#pragma unroll
            for (int off = 1; off < 16; off <<= 1) {
                psum  += __shfl_xor(psum, off);
                pmsum += __shfl_xor(pmsum, off);
            }
            mrun[r] = nm;
            Zr[r] = Zr[r] * alpha + psum;
            Zm[r] = Zm[r] * alpha + pmsum;
#pragma unroll
            for (int d = 0; d < 8; ++d) oacc[d][r] *= alpha;
#pragma unroll
            for (int nt = 0; nt < 4; ++nt)
                PEP[(wave*16 + quad*4 + r) * P_STR + nt*16 + lq] = (short)f2bf(pmv[nt]);
        }
        __syncthreads();   // P visible

        // O += P @ V
#pragma unroll
        for (int kk = 0; kk < 2; ++kk) {
            const bf16x8 pf = *(const bf16x8*)&PEP[(wave*16 + lq) * P_STR + kk*32 + quad*8];
#pragma unroll
            for (int dt = 0; dt < 8; ++dt) {
                const bf16x8 vf = *(const bf16x8*)&Vt[(dt*16 + lq) * VT_STR + kk*32 + quad*8];
                oacc[dt] = __builtin_amdgcn_mfma_f32_16x16x32_bf16(pf, vf, oacc[dt], 0, 0, 0);
            }
        }
    }

    // epilogue: out = O / (Zm + 1e-8 * Z)
#pragma unroll
    for (int r = 0; r < 4; ++r) {
        const int iq = i0 + wave*16 + quad*4 + r;
        const float inv = 1.0f / (Zm[r] + 1e-8f * Zr[r]);
        float* op = out + ((size_t)bh * M_ + iq) * D_;
#pragma unroll
        for (int dt = 0; dt < 8; ++dt)
            op[dt*16 + lq] = oacc[dt][r] * inv;
    }
}

extern "C" void kernel_launch(void* const* d_in, const int* in_sizes, int n_in,
                              void* d_out, int out_size, void* d_ws, size_t ws_size,
                              hipStream_t stream) {
    (void)in_sizes; (void)n_in; (void)out_size; (void)ws_size;
    const float* Q       = (const float*)d_in[0];
    const float* K       = (const float*)d_in[1];
    const float* V       = (const float*)d_in[2];
    const float* hid     = (const float*)d_in[3];
    const float* counter = (const float*)d_in[4];
    const float* pe      = (const float*)d_in[5];
    const float* sw      = (const float*)d_in[6];
    const float* sb      = (const float*)d_in[7];

    float* out    = (float*)d_out;
    float* aux    = out + (size_t)BH_ * M_ * D_;
    float* r0_out = aux + B_;

    float* r0_ws = (float*)d_ws;
    float* tmax  = r0_ws + B_ * L_;

    span_kernel<<<(B_ * L_) / 4, 256, 0, stream>>>(hid, counter, sw, sb, r0_ws, r0_out);
    tilemax_kernel<<<B_ * NT64, 64, 0, stream>>>(r0_ws, tmax);
    aux_kernel<<<B_, 256, 0, stream>>>(r0_ws, aux);
    attn_kernel<<<dim3(M_ / 64, BH_), 256, 0, stream>>>(Q, K, V, pe, r0_ws, tmax, out);
}

// Round 2
// 241.073 us; speedup vs baseline: 1.2118x; 1.2118x over previous
//
#include <hip/hip_runtime.h>
#include <stdint.h>

// SeqAttention: B=4,H=8,M=1024,L=3200,D=128,HID=1024, ATTN_LIM=2048, RAMP=128
#define B_   4
#define H_   8
#define BH_  32
#define M_   1024
#define L_   3200
#define D_   128
#define HID_ 1024
#define NT64 50                 /* L/64 */
#define CAUSAL_K 2175           /* max_mem - M - 1 */
#define POS_OFF  1152           /* L - 2M */
#define SCALE 0.08838834764831845f /* 1/sqrt(128) */
#define NEGV (-3.0e38f)
#define NEGH (-1.0e38f)

typedef short  bf16x8 __attribute__((ext_vector_type(8)));
typedef float  f32x4  __attribute__((ext_vector_type(4)));

__device__ __forceinline__ unsigned short f2bf(float x) {
    union { float f; uint32_t u; } v; v.f = x;
    return (unsigned short)((v.u + 0x7FFFu + ((v.u >> 16) & 1u)) >> 16);
}
__device__ __forceinline__ float bf2f(unsigned short h) {
    union { uint32_t u; float f; } v; v.u = ((uint32_t)h) << 16; return v.f;
}
// truncating pack: low16 = bf16(lo), high16 = bf16(hi) — single v_perm_b32
__device__ __forceinline__ uint32_t pack_bf2(float lo, float hi) {
    union { float f; uint32_t u; } a, b; a.f = lo; b.f = hi;
    return __builtin_amdgcn_perm(b.u, a.u, 0x07060302u);
}

// ---- remaining_offset[b,l] = sigmoid(dot(hid/16, w) + b)*2048 - counter ----
__global__ void span_kernel(const float* __restrict__ hid,
                            const float* __restrict__ counter,
                            const float* __restrict__ sw,
                            const float* __restrict__ sb,
                            float* __restrict__ r0_ws,
                            float* __restrict__ r0_out) {
    const int row  = blockIdx.x * 4 + (threadIdx.x >> 6);   // one wave per (b,l)
    const int lane = threadIdx.x & 63;
    const float* h = hid + (size_t)row * HID_;
    float acc = 0.f;
#pragma unroll
    for (int it = 0; it < 4; ++it) {
        const int k = it * 256 + lane * 4;
        const float4 a = *(const float4*)(h + k);
        const float4 w = *(const float4*)(sw + k);
        acc += a.x*w.x + a.y*w.y + a.z*w.z + a.w*w.w;
    }
#pragma unroll
    for (int off = 32; off; off >>= 1) acc += __shfl_down(acc, off);
    if (lane == 0) {
        const float x  = acc * (1.0f/16.0f) + sb[0];
        const float ms = 2048.0f / (1.0f + __expf(-x));
        const float r0 = ms - counter[row];
        r0_ws[row]  = r0;
        r0_out[row] = r0;
    }
}

// ---- per-(b, 64-wide l-tile) max of remaining_offset, for tile skipping ----
__global__ void tilemax_kernel(const float* __restrict__ r0_ws,
                               float* __restrict__ tmax) {
    const int t = blockIdx.x;
    const int lane = threadIdx.x;
    float v = r0_ws[t * 64 + lane];
#pragma unroll
    for (int off = 32; off; off >>= 1) v = fmaxf(v, __shfl_down(v, off));
    if (lane == 0) tmax[t] = v;
}

// ---- aux_loss: closed-form arithmetic series over m in (r, r+128) ----
__global__ void aux_kernel(const float* __restrict__ r0_ws,
                           float* __restrict__ aux_out) {
    const int b = blockIdx.x, tid = threadIdx.x;
    float s = 0.f;
    for (int l = tid; l < L_; l += 256) {
        const float r = r0_ws[b * L_ + l];
        const int fl = (int)floorf(r);
        int mlo = fl + 1;   if (mlo < 0) mlo = 0;
        int mhi = fl + 128; if (mhi > M_ - 1) mhi = M_ - 1;
        const int n = mhi - mlo + 1;
        if (n > 0) s += (float)n * r - 0.5f * (float)(mlo + mhi) * (float)n;
    }
    __shared__ float red[256];
    red[tid] = s; __syncthreads();
    for (int st = 128; st; st >>= 1) {
        if (tid < st) red[tid] += red[tid + st];
        __syncthreads();
    }
    if (tid == 0) aux_out[b] = red[0] * (1.0f/128.0f) * (1.0f/1024.0f) * 1e-6f;
}

// ---- PE (D,M) f32 -> PET (M,D) bf16, coalesced writes ----
__global__ void pet_kernel(const float* __restrict__ PE,
                           unsigned short* __restrict__ PET) {
    const int tid = threadIdx.x;
    const int c = blockIdx.x * 4 + (tid >> 6);
    const int e = tid & 63;
    const float lo = PE[(2*e)   * M_ + c];
    const float hi = PE[(2*e+1) * M_ + c];
    ((uint32_t*)PET)[c * 64 + e] = pack_bf2(lo, hi);
}

// ================= optimized flash attention =================
#define KS_STR 136   /* 128 + 8 (bf16 elems); must be 8*odd for b128 reads */
#define VT_STR 72    /* 64 + 8 */
#define PE_STR 136
#define P_STR  72
#define T_STR  72

__global__ void __launch_bounds__(256, 2)
attn_kernel(const float* __restrict__ Q, const float* __restrict__ K,
            const float* __restrict__ V, const unsigned short* __restrict__ PET,
            const float* __restrict__ r0g, const float* __restrict__ tmax,
            float* __restrict__ out) {
    __shared__ short Ks[64 * KS_STR];        // K tile [l][d]
    __shared__ short Vt[128 * VT_STR];       // V tile transposed [d][l]
    __shared__ short PEs[64 * PE_STR];       // PE^T tile [c][d]
    __shared__ short Tb[2][64 * T_STR];      // rolling Q@PE tiles [i][c] (wave-private rows)
    __shared__ short Pb[64 * P_STR];         // P tile [m][l]
    __shared__ float r0s[64];
    __shared__ float tfl[NT64];

    const int bh = blockIdx.y;
    const int b  = bh >> 3;
    const int i0 = blockIdx.x << 6;
    const int tid  = threadIdx.x;
    const int wave = tid >> 6;
    const int lane = tid & 63;
    const int lq   = lane & 15;
    const int quad = lane >> 4;
    const int lt_end = min(NT64, (int)blockIdx.x + 35);   // causal bound

    if (tid < NT64) tfl[tid] = tmax[b * NT64 + tid];
    __syncthreads();
    const float live_thresh = (float)(i0 - 128);

    auto next_live = [&](int s) {
        while (s < lt_end && !(tfl[s] > live_thresh)) ++s;
        return s;
    };

    // ---- prefetch registers (tile lt staged here before LDS write) ----
    float4 kp[8];
    float4 vpa[4], vpb[4];
    uint4  pep[4];
    float  r0p = 0.f;

    auto issue_prefetch = [&](int plt) {
        const int l0p = plt << 6;
        const float* kb = K + ((size_t)bh * L_ + l0p) * D_;
        const float* vb = V + ((size_t)bh * L_ + l0p) * D_;
#pragma unroll
        for (int it = 0; it < 8; ++it) {
            const int f = it * 256 + tid;
            kp[it] = *(const float4*)(kb + (f >> 5) * D_ + (f & 31) * 4);
        }
        const int p2 = (tid & 31) * 2;
#pragma unroll
        for (int it = 0; it < 4; ++it) {
            const int c = it * 8 + (tid >> 5);
            vpa[it] = *(const float4*)(vb + (size_t)p2 * D_ + c * 4);
            vpb[it] = *(const float4*)(vb + (size_t)(p2 + 1) * D_ + c * 4);
        }
        const int c0p = l0p - i0 - POS_OFF;
#pragma unroll
        for (int it = 0; it < 4; ++it) {
            const int f = it * 256 + tid;
            const int cg = c0p + (f >> 4);
            if ((unsigned)cg < (unsigned)M_)
                pep[it] = *(const uint4*)(PET + (size_t)cg * D_ + (f & 15) * 8);
            else { pep[it].x = 0; pep[it].y = 0; pep[it].z = 0; pep[it].w = 0; }
        }
        if (tid < 64) r0p = r0g[b * L_ + l0p + tid];
    };

    auto write_stage = [&]() {
#pragma unroll
        for (int it = 0; it < 8; ++it) {
            const int f = it * 256 + tid;
            uint2 w;
            w.x = pack_bf2(kp[it].x, kp[it].y);
            w.y = pack_bf2(kp[it].z, kp[it].w);
            *(uint2*)&Ks[(f >> 5) * KS_STR + (f & 31) * 4] = w;
        }
        const int p2 = (tid & 31) * 2;
#pragma unroll
        for (int it = 0; it < 4; ++it) {
            const int c = it * 8 + (tid >> 5);
            const float* a = (const float*)&vpa[it];
            const float* bb = (const float*)&vpb[it];
#pragma unroll
            for (int j = 0; j < 4; ++j)
                *(uint32_t*)&Vt[(c * 4 + j) * VT_STR + p2] = pack_bf2(a[j], bb[j]);
        }
#pragma unroll
        for (int it = 0; it < 4; ++it) {
            const int f = it * 256 + tid;
            *(uint4*)&PEs[(f >> 4) * PE_STR + (f & 15) * 8] = pep[it];
        }
        if (tid < 64) r0s[tid] = r0p;
    };

    // ---- Q fragments ----
    int lt = next_live(0);
    if (lt < lt_end) issue_prefetch(lt);

    bf16x8 qfrag[4];
    {
        const float* qp = Q + ((size_t)bh * M_ + (i0 + wave * 16 + lq)) * D_;
#pragma unroll
        for (int kk = 0; kk < 4; ++kk) {
            const float4 q0 = *(const float4*)(qp + kk * 32 + quad * 8);
            const float4 q1 = *(const float4*)(qp + kk * 32 + quad * 8 + 4);
            union { bf16x8 v; uint32_t u[4]; } qq;
            qq.u[0] = pack_bf2(q0.x, q0.y); qq.u[1] = pack_bf2(q0.z, q0.w);
            qq.u[2] = pack_bf2(q1.x, q1.y); qq.u[3] = pack_bf2(q1.z, q1.w);
            qfrag[kk] = qq.v;
        }
    }

    auto computeT = [&](short* tb) {
#pragma unroll
        for (int nt = 0; nt < 4; ++nt) {
            f32x4 acc = (f32x4){0.f, 0.f, 0.f, 0.f};
#pragma unroll
            for (int kk = 0; kk < 4; ++kk) {
                const bf16x8 bf = *(const bf16x8*)&PEs[(nt*16 + lq) * PE_STR + kk*32 + quad*8];
                acc = __builtin_amdgcn_mfma_f32_16x16x32_bf16(qfrag[kk], bf, acc, 0, 0, 0);
            }
#pragma unroll
            for (int r = 0; r < 4; ++r) {
                union { float f; uint32_t u; } t; t.f = acc[r];
                tb[(wave*16 + quad*4 + r) * T_STR + nt*16 + lq] = (short)(t.u >> 16);
            }
        }
    };

    f32x4 oacc[8];
#pragma unroll
    for (int d = 0; d < 8; ++d) oacc[d] = (f32x4){0.f, 0.f, 0.f, 0.f};
    float mrun[4] = {NEGV, NEGV, NEGV, NEGV};
    float Zr[4]   = {0.f, 0.f, 0.f, 0.f};
    float Zm[4]   = {0.f, 0.f, 0.f, 0.f};
    int tlo = 0, thi = 1;
    int prev_c0 = -(1 << 30);

    while (lt < lt_end) {
        const int l0 = lt << 6;
        const int c0 = l0 - i0 - POS_OFF;
        const bool need_pos = (c0 + 63 >= 0) && (c0 - 63 <= M_ - 1);
        const bool rolling  = need_pos && (prev_c0 == c0 - 64);

        __syncthreads();                       // sync0: prev LDS reads complete
        write_stage();
        const int ltn = next_live(lt + 1);
        if (ltn < lt_end) issue_prefetch(ltn); // next tile's loads in flight across compute
        __syncthreads();                       // sync1: staging visible

        // S = Q @ K^T
        f32x4 sfrag[4];
#pragma unroll
        for (int nt = 0; nt < 4; ++nt) {
            f32x4 acc = (f32x4){0.f, 0.f, 0.f, 0.f};
#pragma unroll
            for (int kk = 0; kk < 4; ++kk) {
                const bf16x8 bf = *(const bf16x8*)&Ks[(nt*16 + lq) * KS_STR + kk*32 + quad*8];
                acc = __builtin_amdgcn_mfma_f32_16x16x32_bf16(qfrag[kk], bf, acc, 0, 0, 0);
            }
            sfrag[nt] = acc;
        }

        // rel-pos T tiles (Tb rows are wave-private: no barrier needed for Tb itself)
        if (need_pos) {
            if (rolling) {
                const int t = tlo; tlo = thi; thi = t;
                computeT(&Tb[thi][0]);
            } else {
                tlo = 0; thi = 1;
                computeT(&Tb[1][0]);
                // restage PEs with the low tile (head/gap only, ~once per block)
                uint4 lowp[4];
#pragma unroll
                for (int it = 0; it < 4; ++it) {
                    const int f = it * 256 + tid;
                    const int cg = (c0 - 64) + (f >> 4);
                    if ((unsigned)cg < (unsigned)M_)
                        lowp[it] = *(const uint4*)(PET + (size_t)cg * D_ + (f & 15) * 8);
                    else { lowp[it].x = 0; lowp[it].y = 0; lowp[it].z = 0; lowp[it].w = 0; }
                }
                __syncthreads();               // all waves done reading PEs (T-hi)
#pragma unroll
                for (int it = 0; it < 4; ++it) {
                    const int f = it * 256 + tid;
                    *(uint4*)&PEs[(f >> 4) * PE_STR + (f & 15) * 8] = lowp[it];
                }
                __syncthreads();
                computeT(&Tb[0][0]);
            }
            prev_c0 = c0;
        } else {
            prev_c0 = -(1 << 30);
        }

        // masked scores (C-layout: row = quad*4+r, col = nt*16+lq)
        float rv[4];
#pragma unroll
        for (int nt = 0; nt < 4; ++nt) rv[nt] = r0s[nt*16 + lq];

        float sv[4][4], em[4][4];
#pragma unroll
        for (int r = 0; r < 4; ++r) {
            const int iq = i0 + wave*16 + quad*4 + r;
            const float fiq = (float)iq;
#pragma unroll
            for (int nt = 0; nt < 4; ++nt) {
                const int l = l0 + nt*16 + lq;
                float s = sfrag[nt][r];
                const int c = l - iq - POS_OFF;
                if (need_pos && (unsigned)c < (unsigned)M_) {
                    const int cb = c - (c0 - 64);          // in [1,127]
                    const short* tbp = (cb & 64) ? &Tb[thi][0] : &Tb[tlo][0];
                    s += bf2f((unsigned short)tbp[(wave*16 + quad*4 + r) * T_STR + (cb & 63)]);
                }
                const float e = fminf(fmaxf((rv[nt] - fiq) * 0.0078125f + 1.0f, 0.f), 1.f);
                em[r][nt] = e;
                const bool live = (l <= iq + CAUSAL_K) && (e > 0.f);
                sv[r][nt] = live ? s * SCALE : NEGV;
            }
        }

        // online softmax + P (= e * emask) to LDS
#pragma unroll
        for (int r = 0; r < 4; ++r) {
            float v = fmaxf(fmaxf(sv[r][0], sv[r][1]), fmaxf(sv[r][2], sv[r][3]));
#pragma unroll
            for (int off = 1; off < 16; off <<= 1) v = fmaxf(v, __shfl_xor(v, off));
            const float nm = fmaxf(mrun[r], v);
            float alpha = 1.f, psum = 0.f, pmsum = 0.f, pmv[4];
            if (nm > NEGH) {
                alpha = (mrun[r] > NEGH) ? __expf(mrun[r] - nm) : 0.f;
#pragma unroll
                for (int nt = 0; nt < 4; ++nt) {
                    const float p = __expf(sv[r][nt] - nm);   // dead -> 0
                    const float pm = p * em[r][nt];
                    psum += p; pmsum += pm; pmv[nt] = pm;
                }
            } else {
                pmv[0] = pmv[1] = pmv[2] = pmv[3] = 0.f;
            }
#pragma unroll
            for (int off = 1; off < 16; off <<= 1) {
                psum  += __shfl_xor(psum, off);
                pmsum += __shfl_xor(pmsum, off);
            }
            mrun[r] = nm;
            Zr[r] = Zr[r] * alpha + psum;
            Zm[r] = Zm[r] * alpha + pmsum;
#pragma unroll
            for (int d = 0; d < 8; ++d) oacc[d][r] *= alpha;
#pragma unroll
            for (int nt = 0; nt < 4; ++nt) {
                union { float f; uint32_t u; } t; t.f = pmv[nt];
                Pb[(wave*16 + quad*4 + r) * P_STR + nt*16 + lq] = (short)(t.u >> 16);
            }
        }
        __syncthreads();                       // sync2: P visible

        // O += P @ V
#pragma unroll
        for (int kk = 0; kk < 2; ++kk) {
            const bf16x8 pf = *(const bf16x8*)&Pb[(wave*16 + lq) * P_STR + kk*32 + quad*8];
#pragma unroll
            for (int dt = 0; dt < 8; ++dt) {
                const bf16x8 vf = *(const bf16x8*)&Vt[(dt*16 + lq) * VT_STR + kk*32 + quad*8];
                oacc[dt] = __builtin_amdgcn_mfma_f32_16x16x32_bf16(pf, vf, oacc[dt], 0, 0, 0);
            }
        }
        lt = ltn;
    }

    // epilogue: out = O / (Zm + 1e-8 * Z)
#pragma unroll
    for (int r = 0; r < 4; ++r) {
        const int iq = i0 + wave*16 + quad*4 + r;
        const float inv = 1.0f / (Zm[r] + 1e-8f * Zr[r]);
        float* op = out + ((size_t)bh * M_ + iq) * D_;
#pragma unroll
        for (int dt = 0; dt < 8; ++dt)
            op[dt*16 + lq] = oacc[dt][r] * inv;
    }
}

// ================= fallback (round-1 kernel, used only if ws too small) =================
__global__ void __launch_bounds__(256, 2)
attn_fb_kernel(const float* __restrict__ Q, const float* __restrict__ K,
               const float* __restrict__ V, const float* __restrict__ PE,
               const float* __restrict__ r0g, const float* __restrict__ tmax,
               float* __restrict__ out) {
    __shared__ short Ks[64 * KS_STR];
    __shared__ short Vt[128 * VT_STR];
    __shared__ short PEP[64 * PE_STR];
    __shared__ short Tb[2][64 * T_STR];
    __shared__ float r0s[64];

    const int bh = blockIdx.y;
    const int b  = bh >> 3;
    const int i0 = blockIdx.x << 6;
    const int tid  = threadIdx.x;
    const int wave = tid >> 6;
    const int lane = tid & 63;
    const int lq   = lane & 15;
    const int quad = lane >> 4;

    bf16x8 qfrag[4];
    {
        const float* qp = Q + ((size_t)bh * M_ + (i0 + wave * 16 + lq)) * D_;
#pragma unroll
        for (int kk = 0; kk < 4; ++kk) {
            const float* p = qp + kk * 32 + quad * 8;
            bf16x8 f;
#pragma unroll
            for (int j = 0; j < 8; ++j) f[j] = (short)f2bf(p[j]);
            qfrag[kk] = f;
        }
    }

    f32x4 oacc[8];
#pragma unroll
    for (int d = 0; d < 8; ++d) oacc[d] = (f32x4){0.f, 0.f, 0.f, 0.f};
    float mrun[4] = {NEGV, NEGV, NEGV, NEGV};
    float Zr[4]   = {0.f, 0.f, 0.f, 0.f};
    float Zm[4]   = {0.f, 0.f, 0.f, 0.f};

    int tlo = 0, thi = 1;
    int prev_c0 = -100000;

    auto stagePE = [&](int cbase) {
#pragma unroll
        for (int it = 0; it < 8; ++it) {
            const int f4 = it * 256 + tid;
            const int d  = f4 >> 4;
            const int cl = (f4 & 15) << 2;
#pragma unroll
            for (int j = 0; j < 4; ++j) {
                const int cg = cbase + cl + j;
                const float v = (cg >= 0 && cg < M_) ? PE[d * M_ + cg] : 0.f;
                PEP[(cl + j) * PE_STR + d] = (short)f2bf(v);
            }
        }
    };
    auto computeT = [&](short* tb) {
#pragma unroll
        for (int nt = 0; nt < 4; ++nt) {
            f32x4 acc = (f32x4){0.f, 0.f, 0.f, 0.f};
#pragma unroll
            for (int kk = 0; kk < 4; ++kk) {
                const bf16x8 bf = *(const bf16x8*)&PEP[(nt*16 + lq) * PE_STR + kk*32 + quad*8];
                acc = __builtin_amdgcn_mfma_f32_16x16x32_bf16(qfrag[kk], bf, acc, 0, 0, 0);
            }
#pragma unroll
            for (int r = 0; r < 4; ++r)
                tb[(wave*16 + quad*4 + r) * T_STR + nt*16 + lq] = (short)f2bf(acc[r]);
        }
    };

    const int lt_end = min(NT64, (int)blockIdx.x + 35);
    for (int lt = 0; lt < lt_end; ++lt) {
        const int l0 = lt << 6;
        if (!(tmax[b * NT64 + lt] > (float)(i0 - 128))) continue;

        __syncthreads();
        {
            const float* kbase = K + ((size_t)bh * L_ + l0) * D_;
            const float* vbase = V + ((size_t)bh * L_ + l0) * D_;
#pragma unroll
            for (int it = 0; it < 8; ++it) {
                const int f4 = it * 256 + tid;
                const int row = f4 >> 5;
                const int ds  = (f4 & 31) << 2;
                const float4 kv = *(const float4*)(kbase + row * D_ + ds);
                uint2 pk;
                pk.x = (uint32_t)f2bf(kv.x) | ((uint32_t)f2bf(kv.y) << 16);
                pk.y = (uint32_t)f2bf(kv.z) | ((uint32_t)f2bf(kv.w) << 16);
                *(uint2*)&Ks[row * KS_STR + ds] = pk;
                const float4 vv = *(const float4*)(vbase + row * D_ + ds);
                Vt[(ds+0) * VT_STR + row] = (short)f2bf(vv.x);
                Vt[(ds+1) * VT_STR + row] = (short)f2bf(vv.y);
                Vt[(ds+2) * VT_STR + row] = (short)f2bf(vv.z);
                Vt[(ds+3) * VT_STR + row] = (short)f2bf(vv.w);
            }
            if (tid < 64) r0s[tid] = r0g[b * L_ + l0 + tid];
        }

        const int c0 = l0 - i0 - POS_OFF;
        const bool need_pos = (c0 + 63 >= 0) && (c0 - 63 <= M_ - 1);
        if (need_pos) {
            if (prev_c0 == c0 - 64) {
                const int t = tlo; tlo = thi; thi = t;
                stagePE(c0);
                __syncthreads();
                computeT(&Tb[thi][0]);
            } else {
                stagePE(c0 - 64);
                __syncthreads();
                computeT(&Tb[0][0]);
                __syncthreads();
                stagePE(c0);
                __syncthreads();
                computeT(&Tb[1][0]);
                tlo = 0; thi = 1;
            }
            prev_c0 = c0;
        } else {
            __syncthreads();
        }

        f32x4 sfrag[4];
#pragma unroll
        for (int nt = 0; nt < 4; ++nt) {
            f32x4 acc = (f32x4){0.f, 0.f, 0.f, 0.f};
#pragma unroll
            for (int kk = 0; kk < 4; ++kk) {
                const bf16x8 bf = *(const bf16x8*)&Ks[(nt*16 + lq) * KS_STR + kk*32 + quad*8];
                acc = __builtin_amdgcn_mfma_f32_16x16x32_bf16(qfrag[kk], bf, acc, 0, 0, 0);
            }
            sfrag[nt] = acc;
        }
        __syncthreads();

        float sv[4][4];
#pragma unroll
        for (int r = 0; r < 4; ++r) {
            const int iq = i0 + wave*16 + quad*4 + r;
#pragma unroll
            for (int nt = 0; nt < 4; ++nt) {
                const int l = l0 + nt*16 + lq;
                float s = sfrag[nt][r];
                const int c = l - iq - POS_OFF;
                if (c >= 0 && c < M_) {
                    const int cb = c - (c0 - 64);
                    const short* tbp = (cb & 64) ? &Tb[thi][0] : &Tb[tlo][0];
                    s += bf2f((unsigned short)tbp[(wave*16 + quad*4 + r) * T_STR + (cb & 63)]);
                }
                const float e = fminf(fmaxf((r0s[nt*16 + lq] - (float)iq) * 0.0078125f + 1.0f, 0.f), 1.f);
                const bool live = (l <= iq + CAUSAL_K) && (e > 0.f);
                sv[r][nt] = live ? s * SCALE : NEGV;
            }
        }

#pragma unroll
        for (int r = 0; r < 4; ++r) {
            float v = fmaxf(fmaxf(sv[r][0], sv[r][1]), fmaxf(sv[r][2], sv[r][3]));
#pragma unroll
            for (int off = 1; off < 16; off <<= 1) v = fmaxf(v, __shfl_xor(v, off));
            const float nm = fmaxf(mrun[r], v);
            float alpha, pmv[4];
            float psum = 0.f, pmsum = 0.f;
            if (nm > NEGH) {
                alpha = (mrun[r] > NEGH) ? __expf(mrun[r] - nm) : 0.f;
                const int iq = i0 + wave*16 + quad*4 + r;
#pragma unroll
                for (int nt = 0; nt < 4; ++nt) {
                    const float p = __expf(sv[r][nt] - nm);
                    const float e = fminf(fmaxf((r0s[nt*16 + lq] - (float)iq) * 0.0078125f + 1.0f, 0.f), 1.f);
                    const float pm = p * e;
                    psum += p; pmsum += pm; pmv[nt] = pm;
                }
            } else {
                alpha = 1.f;
                pmv[0] = pmv[1] = pmv[2] = pmv[3] = 0.f;
            }
#pragma unroll
            for (int off = 1; off < 16; off <<= 1) {
                psum  += __shfl_xor(psum, off);
                pmsum += __shfl_xor(pmsum, off);
            }
            mrun[r] = nm;
            Zr[r] = Zr[r] * alpha + psum;
            Zm[r] = Zm[r] * alpha + pmsum;
#pragma unroll
            for (int d = 0; d < 8; ++d) oacc[d][r] *= alpha;
#pragma unroll
            for (int nt = 0; nt < 4; ++nt)
                PEP[(wave*16 + quad*4 + r) * P_STR + nt*16 + lq] = (short)f2bf(pmv[nt]);
        }
        __syncthreads();

#pragma unroll
        for (int kk = 0; kk < 2; ++kk) {
            const bf16x8 pf = *(const bf16x8*)&PEP[(wave*16 + lq) * P_STR + kk*32 + quad*8];
#pragma unroll
            for (int dt = 0; dt < 8; ++dt) {
                const bf16x8 vf = *(const bf16x8*)&Vt[(dt*16 + lq) * VT_STR + kk*32 + quad*8];
                oacc[dt] = __builtin_amdgcn_mfma_f32_16x16x32_bf16(pf, vf, oacc[dt], 0, 0, 0);
            }
        }
    }

#pragma unroll
    for (int r = 0; r < 4; ++r) {
        const int iq = i0 + wave*16 + quad*4 + r;
        const float inv = 1.0f / (Zm[r] + 1e-8f * Zr[r]);
        float* op = out + ((size_t)bh * M_ + iq) * D_;
#pragma unroll
        for (int dt = 0; dt < 8; ++dt)
            op[dt*16 + lq] = oacc[dt][r] * inv;
    }
}

extern "C" void kernel_launch(void* const* d_in, const int* in_sizes, int n_in,
                              void* d_out, int out_size, void* d_ws, size_t ws_size,
                              hipStream_t stream) {
    (void)in_sizes; (void)n_in; (void)out_size;
    const float* Q       = (const float*)d_in[0];
    const float* K       = (const float*)d_in[1];
    const float* V       = (const float*)d_in[2];
    const float* hid     = (const float*)d_in[3];
    const float* counter = (const float*)d_in[4];
    const float* pe      = (const float*)d_in[5];
    const float* sw      = (const float*)d_in[6];
    const float* sb      = (const float*)d_in[7];

    float* out    = (float*)d_out;
    float* aux    = out + (size_t)BH_ * M_ * D_;
    float* r0_out = aux + B_;

    float* r0_ws = (float*)d_ws;                         // 12800 floats
    float* tmax  = r0_ws + B_ * L_;                      // 200 floats
    unsigned short* PET = (unsigned short*)(r0_ws + 13056); // 1024*128 bf16, 16B-aligned
    const bool use_pet = ws_size >= (size_t)(13056 * 4 + M_ * D_ * 2);

    span_kernel<<<(B_ * L_) / 4, 256, 0, stream>>>(hid, counter, sw, sb, r0_ws, r0_out);
    tilemax_kernel<<<B_ * NT64, 64, 0, stream>>>(r0_ws, tmax);
    aux_kernel<<<B_, 256, 0, stream>>>(r0_ws, aux);
    if (use_pet) {
        pet_kernel<<<M_ / 4, 256, 0, stream>>>(pe, PET);
        attn_kernel<<<dim3(M_ / 64, BH_), 256, 0, stream>>>(Q, K, V, PET, r0_ws, tmax, out);
    } else {
        attn_fb_kernel<<<dim3(M_ / 64, BH_), 256, 0, stream>>>(Q, K, V, pe, r0_ws, tmax, out);
    }
}

// Round 3
// 238.196 us; speedup vs baseline: 1.2265x; 1.0121x over previous
//
#include <hip/hip_runtime.h>
#include <stdint.h>

// SeqAttention: B=4,H=8,M=1024,L=3200,D=128,HID=1024, ATTN_LIM=2048, RAMP=128
#define B_   4
#define H_   8
#define BH_  32
#define M_   1024
#define L_   3200
#define D_   128
#define HID_ 1024
#define NT64 50                 /* L/64 */
#define CAUSAL_K 2175           /* max_mem - M - 1 */
#define POS_OFF  1152           /* L - 2M */
#define SCALE 0.08838834764831845f /* 1/sqrt(128) */
#define NEGV (-3.0e38f)
#define NEGH (-1.0e38f)

typedef short  bf16x8 __attribute__((ext_vector_type(8)));
typedef float  f32x4  __attribute__((ext_vector_type(4)));

__device__ __forceinline__ unsigned short f2bf(float x) {
    union { float f; uint32_t u; } v; v.f = x;
    return (unsigned short)((v.u + 0x7FFFu + ((v.u >> 16) & 1u)) >> 16);
}
__device__ __forceinline__ float bf2f(unsigned short h) {
    union { uint32_t u; float f; } v; v.u = ((uint32_t)h) << 16; return v.f;
}
// truncating pack: low16 = bf16(lo), high16 = bf16(hi) — single v_perm_b32
__device__ __forceinline__ uint32_t pack_bf2(float lo, float hi) {
    union { float f; uint32_t u; } a, b; a.f = lo; b.f = hi;
    return __builtin_amdgcn_perm(b.u, a.u, 0x07060302u);
}

// ---- DPP 16-lane (DPP "row") reductions: pure VALU, no LDS pipe ----
// xor-generators: 0xB1 = quad_perm[1,0,3,2] (xor1), 0x4E = quad_perm[2,3,0,1]
// (xor2), 0x141 = row_half_mirror (xor7), 0x140 = row_mirror (xor15).
// {1,2,7,15} generate all of F2^4 -> full 16-lane reduction in 4 steps.
template <int CTRL>
__device__ __forceinline__ float dpp_movf(float x) {
    union { float f; int i; } u; u.f = x;
    u.i = __builtin_amdgcn_update_dpp(0, u.i, CTRL, 0xF, 0xF, true);
    return u.f;
}
__device__ __forceinline__ float row_max16(float x) {
    x = fmaxf(x, dpp_movf<0xB1>(x));
    x = fmaxf(x, dpp_movf<0x4E>(x));
    x = fmaxf(x, dpp_movf<0x141>(x));
    x = fmaxf(x, dpp_movf<0x140>(x));
    return x;
}
__device__ __forceinline__ float row_sum16(float x) {
    x += dpp_movf<0xB1>(x);
    x += dpp_movf<0x4E>(x);
    x += dpp_movf<0x141>(x);
    x += dpp_movf<0x140>(x);
    return x;
}

// ---- remaining_offset[b,l] = sigmoid(dot(hid/16, w) + b)*2048 - counter ----
__global__ void span_kernel(const float* __restrict__ hid,
                            const float* __restrict__ counter,
                            const float* __restrict__ sw,
                            const float* __restrict__ sb,
                            float* __restrict__ r0_ws,
                            float* __restrict__ r0_out) {
    const int row  = blockIdx.x * 4 + (threadIdx.x >> 6);   // one wave per (b,l)
    const int lane = threadIdx.x & 63;
    const float* h = hid + (size_t)row * HID_;
    float acc = 0.f;
#pragma unroll
    for (int it = 0; it < 4; ++it) {
        const int k = it * 256 + lane * 4;
        const float4 a = *(const float4*)(h + k);
        const float4 w = *(const float4*)(sw + k);
        acc += a.x*w.x + a.y*w.y + a.z*w.z + a.w*w.w;
    }
#pragma unroll
    for (int off = 32; off; off >>= 1) acc += __shfl_down(acc, off);
    if (lane == 0) {
        const float x  = acc * (1.0f/16.0f) + sb[0];
        const float ms = 2048.0f / (1.0f + __expf(-x));
        const float r0 = ms - counter[row];
        r0_ws[row]  = r0;
        r0_out[row] = r0;
    }
}

// ---- per-(b, 64-wide l-tile) max of remaining_offset, for tile skipping ----
__global__ void tilemax_kernel(const float* __restrict__ r0_ws,
                               float* __restrict__ tmax) {
    const int t = blockIdx.x;
    const int lane = threadIdx.x;
    float v = r0_ws[t * 64 + lane];
#pragma unroll
    for (int off = 32; off; off >>= 1) v = fmaxf(v, __shfl_down(v, off));
    if (lane == 0) tmax[t] = v;
}

// ---- aux_loss: closed-form arithmetic series over m in (r, r+128) ----
__global__ void aux_kernel(const float* __restrict__ r0_ws,
                           float* __restrict__ aux_out) {
    const int b = blockIdx.x, tid = threadIdx.x;
    float s = 0.f;
    for (int l = tid; l < L_; l += 256) {
        const float r = r0_ws[b * L_ + l];
        const int fl = (int)floorf(r);
        int mlo = fl + 1;   if (mlo < 0) mlo = 0;
        int mhi = fl + 128; if (mhi > M_ - 1) mhi = M_ - 1;
        const int n = mhi - mlo + 1;
        if (n > 0) s += (float)n * r - 0.5f * (float)(mlo + mhi) * (float)n;
    }
    __shared__ float red[256];
    red[tid] = s; __syncthreads();
    for (int st = 128; st; st >>= 1) {
        if (tid < st) red[tid] += red[tid + st];
        __syncthreads();
    }
    if (tid == 0) aux_out[b] = red[0] * (1.0f/128.0f) * (1.0f/1024.0f) * 1e-6f;
}

// ---- PE (D,M) f32 -> PET (M,D) bf16, coalesced writes ----
__global__ void pet_kernel(const float* __restrict__ PE,
                           unsigned short* __restrict__ PET) {
    const int tid = threadIdx.x;
    const int c = blockIdx.x * 4 + (tid >> 6);
    const int e = tid & 63;
    const float lo = PE[(2*e)   * M_ + c];
    const float hi = PE[(2*e+1) * M_ + c];
    ((uint32_t*)PET)[c * 64 + e] = pack_bf2(lo, hi);
}

// ================= optimized flash attention =================
#define KS_STR 136   /* 128 + 8 (bf16 elems); 8*odd for b128 bank spread */
#define VT_STR 72    /* 64 + 8 */
#define PE_STR 136
#define P_STR  72
#define T_STR  72

__global__ void __launch_bounds__(256, 2)
attn_kernel(const float* __restrict__ Q, const float* __restrict__ K,
            const float* __restrict__ V, const unsigned short* __restrict__ PET,
            const float* __restrict__ r0g, const float* __restrict__ tmax,
            float* __restrict__ out) {
    __shared__ short Ks[64 * KS_STR];        // K tile [l][d]
    __shared__ short Vt[128 * VT_STR];       // V tile transposed [d][l]
    __shared__ short PEs[64 * PE_STR];       // PE^T tile [c][d]
    __shared__ short Tb[2][64 * T_STR];      // rolling Q@PE tiles [i][c] (wave-private rows)
    __shared__ short Pb[64 * P_STR];         // P tile [m][l] (wave-private rows)
    __shared__ float r0s[64];
    __shared__ float tfl[NT64];

    const int bh = blockIdx.y;
    const int b  = bh >> 3;
    const int i0 = blockIdx.x << 6;
    const int tid  = threadIdx.x;
    const int wave = tid >> 6;
    const int lane = tid & 63;
    const int lq   = lane & 15;
    const int quad = lane >> 4;
    const int lt_end = min(NT64, (int)blockIdx.x + 35);   // causal bound

    if (tid < NT64) tfl[tid] = tmax[b * NT64 + tid];
    __syncthreads();
    const float live_thresh = (float)(i0 - 128);

    auto next_live = [&](int s) {
        while (s < lt_end && !(tfl[s] > live_thresh)) ++s;
        return s;
    };

    // ---- prefetch registers (tile lt staged here before LDS write) ----
    float4 kp[8];
    float4 vpa[4], vpb[4];
    uint4  pep[4];
    float  r0p = 0.f;

    auto issue_prefetch = [&](int plt) {
        const int l0p = plt << 6;
        const float* kb = K + ((size_t)bh * L_ + l0p) * D_;
        const float* vb = V + ((size_t)bh * L_ + l0p) * D_;
#pragma unroll
        for (int it = 0; it < 8; ++it) {
            const int f = it * 256 + tid;
            kp[it] = *(const float4*)(kb + (f >> 5) * D_ + (f & 31) * 4);
        }
        const int p2 = (tid & 31) * 2;
#pragma unroll
        for (int it = 0; it < 4; ++it) {
            const int c = it * 8 + (tid >> 5);
            vpa[it] = *(const float4*)(vb + (size_t)p2 * D_ + c * 4);
            vpb[it] = *(const float4*)(vb + (size_t)(p2 + 1) * D_ + c * 4);
        }
        const int c0p = l0p - i0 - POS_OFF;
#pragma unroll
        for (int it = 0; it < 4; ++it) {
            const int f = it * 256 + tid;
            const int cg = c0p + (f >> 4);
            if ((unsigned)cg < (unsigned)M_)
                pep[it] = *(const uint4*)(PET + (size_t)cg * D_ + (f & 15) * 8);
            else { pep[it].x = 0; pep[it].y = 0; pep[it].z = 0; pep[it].w = 0; }
        }
        if (tid < 64) r0p = r0g[b * L_ + l0p + tid];
    };

    auto write_stage = [&]() {
#pragma unroll
        for (int it = 0; it < 8; ++it) {
            const int f = it * 256 + tid;
            uint2 w;
            w.x = pack_bf2(kp[it].x, kp[it].y);
            w.y = pack_bf2(kp[it].z, kp[it].w);
            *(uint2*)&Ks[(f >> 5) * KS_STR + (f & 31) * 4] = w;
        }
        const int p2 = (tid & 31) * 2;
#pragma unroll
        for (int it = 0; it < 4; ++it) {
            const int c = it * 8 + (tid >> 5);
            const float* a = (const float*)&vpa[it];
            const float* bb = (const float*)&vpb[it];
#pragma unroll
            for (int j = 0; j < 4; ++j)
                *(uint32_t*)&Vt[(c * 4 + j) * VT_STR + p2] = pack_bf2(a[j], bb[j]);
        }
#pragma unroll
        for (int it = 0; it < 4; ++it) {
            const int f = it * 256 + tid;
            *(uint4*)&PEs[(f >> 4) * PE_STR + (f & 15) * 8] = pep[it];
        }
        if (tid < 64) r0s[tid] = r0p;
    };

    // ---- Q fragments ----
    int lt = next_live(0);
    if (lt < lt_end) issue_prefetch(lt);

    bf16x8 qfrag[4];
    {
        const float* qp = Q + ((size_t)bh * M_ + (i0 + wave * 16 + lq)) * D_;
#pragma unroll
        for (int kk = 0; kk < 4; ++kk) {
            const float4 q0 = *(const float4*)(qp + kk * 32 + quad * 8);
            const float4 q1 = *(const float4*)(qp + kk * 32 + quad * 8 + 4);
            union { bf16x8 v; uint32_t u[4]; } qq;
            qq.u[0] = pack_bf2(q0.x, q0.y); qq.u[1] = pack_bf2(q0.z, q0.w);
            qq.u[2] = pack_bf2(q1.x, q1.y); qq.u[3] = pack_bf2(q1.z, q1.w);
            qfrag[kk] = qq.v;
        }
    }

    auto computeT = [&](short* tb) {
#pragma unroll
        for (int nt = 0; nt < 4; ++nt) {
            f32x4 acc = (f32x4){0.f, 0.f, 0.f, 0.f};
#pragma unroll
            for (int kk = 0; kk < 4; ++kk) {
                const bf16x8 bf = *(const bf16x8*)&PEs[(nt*16 + lq) * PE_STR + kk*32 + quad*8];
                acc = __builtin_amdgcn_mfma_f32_16x16x32_bf16(qfrag[kk], bf, acc, 0, 0, 0);
            }
#pragma unroll
            for (int r = 0; r < 4; ++r) {
                union { float f; uint32_t u; } t; t.f = acc[r];
                tb[(wave*16 + quad*4 + r) * T_STR + nt*16 + lq] = (short)(t.u >> 16);
            }
        }
    };

    f32x4 oacc[8];
#pragma unroll
    for (int d = 0; d < 8; ++d) oacc[d] = (f32x4){0.f, 0.f, 0.f, 0.f};
    float mrun[4] = {NEGV, NEGV, NEGV, NEGV};
    float Zr[4]   = {0.f, 0.f, 0.f, 0.f};
    float Zm[4]   = {0.f, 0.f, 0.f, 0.f};
    int tlo = 0, thi = 1;
    int prev_c0 = -(1 << 30);

    while (lt < lt_end) {
        const int l0 = lt << 6;
        const int c0 = l0 - i0 - POS_OFF;
        const bool need_pos = (c0 + 63 >= 0) && (c0 - 63 <= M_ - 1);
        const bool rolling  = need_pos && (prev_c0 == c0 - 64);

        __syncthreads();                       // sync0: prev LDS reads complete
        write_stage();
        const int ltn = next_live(lt + 1);
        if (ltn < lt_end) issue_prefetch(ltn); // next tile's loads in flight across compute
        __syncthreads();                       // sync1: staging visible

        // S = Q @ K^T
        f32x4 sfrag[4];
#pragma unroll
        for (int nt = 0; nt < 4; ++nt) {
            f32x4 acc = (f32x4){0.f, 0.f, 0.f, 0.f};
#pragma unroll
            for (int kk = 0; kk < 4; ++kk) {
                const bf16x8 bf = *(const bf16x8*)&Ks[(nt*16 + lq) * KS_STR + kk*32 + quad*8];
                acc = __builtin_amdgcn_mfma_f32_16x16x32_bf16(qfrag[kk], bf, acc, 0, 0, 0);
            }
            sfrag[nt] = acc;
        }

        // rel-pos T tiles (Tb rows are wave-private: no barrier needed)
        if (need_pos) {
            if (rolling) {
                const int t = tlo; tlo = thi; thi = t;
                computeT(&Tb[thi][0]);
            } else {
                tlo = 0; thi = 1;
                computeT(&Tb[1][0]);
                // restage PEs with the low tile (head/gap only, ~once per block)
                uint4 lowp[4];
#pragma unroll
                for (int it = 0; it < 4; ++it) {
                    const int f = it * 256 + tid;
                    const int cg = (c0 - 64) + (f >> 4);
                    if ((unsigned)cg < (unsigned)M_)
                        lowp[it] = *(const uint4*)(PET + (size_t)cg * D_ + (f & 15) * 8);
                    else { lowp[it].x = 0; lowp[it].y = 0; lowp[it].z = 0; lowp[it].w = 0; }
                }
                __syncthreads();               // all waves done reading PEs (T-hi)
#pragma unroll
                for (int it = 0; it < 4; ++it) {
                    const int f = it * 256 + tid;
                    *(uint4*)&PEs[(f >> 4) * PE_STR + (f & 15) * 8] = lowp[it];
                }
                __syncthreads();
                computeT(&Tb[0][0]);
            }
            prev_c0 = c0;
        } else {
            prev_c0 = -(1 << 30);
        }

        // masked scores (C-layout: row = quad*4+r, col = nt*16+lq)
        float rv[4];
#pragma unroll
        for (int nt = 0; nt < 4; ++nt) rv[nt] = r0s[nt*16 + lq];

        float sv[4][4], em[4][4];
#pragma unroll
        for (int r = 0; r < 4; ++r) {
            const int iq = i0 + wave*16 + quad*4 + r;
            const float fiq = (float)iq;
#pragma unroll
            for (int nt = 0; nt < 4; ++nt) {
                const int l = l0 + nt*16 + lq;
                float s = sfrag[nt][r];
                const int c = l - iq - POS_OFF;
                if (need_pos && (unsigned)c < (unsigned)M_) {
                    const int cb = c - (c0 - 64);          // in [1,127]
                    const short* tbp = (cb & 64) ? &Tb[thi][0] : &Tb[tlo][0];
                    s += bf2f((unsigned short)tbp[(wave*16 + quad*4 + r) * T_STR + (cb & 63)]);
                }
                const float e = fminf(fmaxf((rv[nt] - fiq) * 0.0078125f + 1.0f, 0.f), 1.f);
                em[r][nt] = e;
                const bool live = (l <= iq + CAUSAL_K) && (e > 0.f);
                sv[r][nt] = live ? s * SCALE : NEGV;
            }
        }

        // online softmax + P (= e * emask) to LDS — DPP reductions, no LDS pipe
#pragma unroll
        for (int r = 0; r < 4; ++r) {
            float v = fmaxf(fmaxf(sv[r][0], sv[r][1]), fmaxf(sv[r][2], sv[r][3]));
            v = row_max16(v);
            const float nm = fmaxf(mrun[r], v);
            float alpha = 1.f, psum = 0.f, pmsum = 0.f, pmv[4];
            if (nm > NEGH) {
                alpha = (mrun[r] > NEGH) ? __expf(mrun[r] - nm) : 0.f;
#pragma unroll
                for (int nt = 0; nt < 4; ++nt) {
                    const float p = __expf(sv[r][nt] - nm);   // dead -> 0
                    const float pm = p * em[r][nt];
                    psum += p; pmsum += pm; pmv[nt] = pm;
                }
            } else {
                pmv[0] = pmv[1] = pmv[2] = pmv[3] = 0.f;
            }
            psum  = row_sum16(psum);
            pmsum = row_sum16(pmsum);
            mrun[r] = nm;
            Zr[r] = Zr[r] * alpha + psum;
            Zm[r] = Zm[r] * alpha + pmsum;
#pragma unroll
            for (int d = 0; d < 8; ++d) oacc[d][r] *= alpha;
#pragma unroll
            for (int nt = 0; nt < 4; ++nt) {
                union { float f; uint32_t u; } t; t.f = pmv[nt];
                Pb[(wave*16 + quad*4 + r) * P_STR + nt*16 + lq] = (short)(t.u >> 16);
            }
        }
        // NOTE: no barrier here — Pb rows are wave-private (writer rows
        // wave*16+quad*4+r and reader rows wave*16+lq are the same 16-row
        // strip); within-wave LDS ordering + lgkmcnt suffice.

        // O += P @ V
#pragma unroll
        for (int kk = 0; kk < 2; ++kk) {
            const bf16x8 pf = *(const bf16x8*)&Pb[(wave*16 + lq) * P_STR + kk*32 + quad*8];
#pragma unroll
            for (int dt = 0; dt < 8; ++dt) {
                const bf16x8 vf = *(const bf16x8*)&Vt[(dt*16 + lq) * VT_STR + kk*32 + quad*8];
                oacc[dt] = __builtin_amdgcn_mfma_f32_16x16x32_bf16(pf, vf, oacc[dt], 0, 0, 0);
            }
        }
        lt = ltn;
    }

    // epilogue: out = O / (Zm + 1e-8 * Z)
#pragma unroll
    for (int r = 0; r < 4; ++r) {
        const int iq = i0 + wave*16 + quad*4 + r;
        const float inv = 1.0f / (Zm[r] + 1e-8f * Zr[r]);
        float* op = out + ((size_t)bh * M_ + iq) * D_;
#pragma unroll
        for (int dt = 0; dt < 8; ++dt)
            op[dt*16 + lq] = oacc[dt][r] * inv;
    }
}

// ================= fallback (only if ws too small for PET) =================
__global__ void __launch_bounds__(256, 2)
attn_fb_kernel(const float* __restrict__ Q, const float* __restrict__ K,
               const float* __restrict__ V, const float* __restrict__ PE,
               const float* __restrict__ r0g, const float* __restrict__ tmax,
               float* __restrict__ out) {
    __shared__ short Ks[64 * KS_STR];
    __shared__ short Vt[128 * VT_STR];
    __shared__ short PEP[64 * PE_STR];
    __shared__ short Tb[2][64 * T_STR];
    __shared__ float r0s[64];

    const int bh = blockIdx.y;
    const int b  = bh >> 3;
    const int i0 = blockIdx.x << 6;
    const int tid  = threadIdx.x;
    const int wave = tid >> 6;
    const int lane = tid & 63;
    const int lq   = lane & 15;
    const int quad = lane >> 4;

    bf16x8 qfrag[4];
    {
        const float* qp = Q + ((size_t)bh * M_ + (i0 + wave * 16 + lq)) * D_;
#pragma unroll
        for (int kk = 0; kk < 4; ++kk) {
            const float* p = qp + kk * 32 + quad * 8;
            bf16x8 f;
#pragma unroll
            for (int j = 0; j < 8; ++j) f[j] = (short)f2bf(p[j]);
            qfrag[kk] = f;
        }
    }

    f32x4 oacc[8];
#pragma unroll
    for (int d = 0; d < 8; ++d) oacc[d] = (f32x4){0.f, 0.f, 0.f, 0.f};
    float mrun[4] = {NEGV, NEGV, NEGV, NEGV};
    float Zr[4]   = {0.f, 0.f, 0.f, 0.f};
    float Zm[4]   = {0.f, 0.f, 0.f, 0.f};

    int tlo = 0, thi = 1;
    int prev_c0 = -100000;

    auto stagePE = [&](int cbase) {
#pragma unroll
        for (int it = 0; it < 8; ++it) {
            const int f4 = it * 256 + tid;
            const int d  = f4 >> 4;
            const int cl = (f4 & 15) << 2;
#pragma unroll
            for (int j = 0; j < 4; ++j) {
                const int cg = cbase + cl + j;
                const float v = (cg >= 0 && cg < M_) ? PE[d * M_ + cg] : 0.f;
                PEP[(cl + j) * PE_STR + d] = (short)f2bf(v);
            }
        }
    };
    auto computeT = [&](short* tb) {
#pragma unroll
        for (int nt = 0; nt < 4; ++nt) {
            f32x4 acc = (f32x4){0.f, 0.f, 0.f, 0.f};
#pragma unroll
            for (int kk = 0; kk < 4; ++kk) {
                const bf16x8 bf = *(const bf16x8*)&PEP[(nt*16 + lq) * PE_STR + kk*32 + quad*8];
                acc = __builtin_amdgcn_mfma_f32_16x16x32_bf16(qfrag[kk], bf, acc, 0, 0, 0);
            }
#pragma unroll
            for (int r = 0; r < 4; ++r)
                tb[(wave*16 + quad*4 + r) * T_STR + nt*16 + lq] = (short)f2bf(acc[r]);
        }
    };

    const int lt_end = min(NT64, (int)blockIdx.x + 35);
    for (int lt = 0; lt < lt_end; ++lt) {
        const int l0 = lt << 6;
        if (!(tmax[b * NT64 + lt] > (float)(i0 - 128))) continue;

        __syncthreads();
        {
            const float* kbase = K + ((size_t)bh * L_ + l0) * D_;
            const float* vbase = V + ((size_t)bh * L_ + l0) * D_;
#pragma unroll
            for (int it = 0; it < 8; ++it) {
                const int f4 = it * 256 + tid;
                const int row = f4 >> 5;
                const int ds  = (f4 & 31) << 2;
                const float4 kv = *(const float4*)(kbase + row * D_ + ds);
                uint2 pk;
                pk.x = (uint32_t)f2bf(kv.x) | ((uint32_t)f2bf(kv.y) << 16);
                pk.y = (uint32_t)f2bf(kv.z) | ((uint32_t)f2bf(kv.w) << 16);
                *(uint2*)&Ks[row * KS_STR + ds] = pk;
                const float4 vv = *(const float4*)(vbase + row * D_ + ds);
                Vt[(ds+0) * VT_STR + row] = (short)f2bf(vv.x);
                Vt[(ds+1) * VT_STR + row] = (short)f2bf(vv.y);
                Vt[(ds+2) * VT_STR + row] = (short)f2bf(vv.z);
                Vt[(ds+3) * VT_STR + row] = (short)f2bf(vv.w);
            }
            if (tid < 64) r0s[tid] = r0g[b * L_ + l0 + tid];
        }

        const int c0 = l0 - i0 - POS_OFF;
        const bool need_pos = (c0 + 63 >= 0) && (c0 - 63 <= M_ - 1);
        if (need_pos) {
            if (prev_c0 == c0 - 64) {
                const int t = tlo; tlo = thi; thi = t;
                stagePE(c0);
                __syncthreads();
                computeT(&Tb[thi][0]);
            } else {
                stagePE(c0 - 64);
                __syncthreads();
                computeT(&Tb[0][0]);
                __syncthreads();
                stagePE(c0);
                __syncthreads();
                computeT(&Tb[1][0]);
                tlo = 0; thi = 1;
            }
            prev_c0 = c0;
        } else {
            __syncthreads();
        }

        f32x4 sfrag[4];
#pragma unroll
        for (int nt = 0; nt < 4; ++nt) {
            f32x4 acc = (f32x4){0.f, 0.f, 0.f, 0.f};
#pragma unroll
            for (int kk = 0; kk < 4; ++kk) {
                const bf16x8 bf = *(const bf16x8*)&Ks[(nt*16 + lq) * KS_STR + kk*32 + quad*8];
                acc = __builtin_amdgcn_mfma_f32_16x16x32_bf16(qfrag[kk], bf, acc, 0, 0, 0);
            }
            sfrag[nt] = acc;
        }
        __syncthreads();

        float sv[4][4];
#pragma unroll
        for (int r = 0; r < 4; ++r) {
            const int iq = i0 + wave*16 + quad*4 + r;
#pragma unroll
            for (int nt = 0; nt < 4; ++nt) {
                const int l = l0 + nt*16 + lq;
                float s = sfrag[nt][r];
                const int c = l - iq - POS_OFF;
                if (c >= 0 && c < M_) {
                    const int cb = c - (c0 - 64);
                    const short* tbp = (cb & 64) ? &Tb[thi][0] : &Tb[tlo][0];
                    s += bf2f((unsigned short)tbp[(wave*16 + quad*4 + r) * T_STR + (cb & 63)]);
                }
                const float e = fminf(fmaxf((r0s[nt*16 + lq] - (float)iq) * 0.0078125f + 1.0f, 0.f), 1.f);
                const bool live = (l <= iq + CAUSAL_K) && (e > 0.f);
                sv[r][nt] = live ? s * SCALE : NEGV;
            }
        }

#pragma unroll
        for (int r = 0; r < 4; ++r) {
            float v = fmaxf(fmaxf(sv[r][0], sv[r][1]), fmaxf(sv[r][2], sv[r][3]));
            v = row_max16(v);
            const float nm = fmaxf(mrun[r], v);
            float alpha, pmv[4];
            float psum = 0.f, pmsum = 0.f;
            if (nm > NEGH) {
                alpha = (mrun[r] > NEGH) ? __expf(mrun[r] - nm) : 0.f;
                const int iq = i0 + wave*16 + quad*4 + r;
#pragma unroll
                for (int nt = 0; nt < 4; ++nt) {
                    const float p = __expf(sv[r][nt] - nm);
                    const float e = fminf(fmaxf((r0s[nt*16 + lq] - (float)iq) * 0.0078125f + 1.0f, 0.f), 1.f);
                    const float pm = p * e;
                    psum += p; pmsum += pm; pmv[nt] = pm;
                }
            } else {
                alpha = 1.f;
                pmv[0] = pmv[1] = pmv[2] = pmv[3] = 0.f;
            }
            psum  = row_sum16(psum);
            pmsum = row_sum16(pmsum);
            mrun[r] = nm;
            Zr[r] = Zr[r] * alpha + psum;
            Zm[r] = Zm[r] * alpha + pmsum;
#pragma unroll
            for (int d = 0; d < 8; ++d) oacc[d][r] *= alpha;
#pragma unroll
            for (int nt = 0; nt < 4; ++nt)
                PEP[(wave*16 + quad*4 + r) * P_STR + nt*16 + lq] = (short)f2bf(pmv[nt]);
        }
        __syncthreads();

#pragma unroll
        for (int kk = 0; kk < 2; ++kk) {
            const bf16x8 pf = *(const bf16x8*)&PEP[(wave*16 + lq) * P_STR + kk*32 + quad*8];
#pragma unroll
            for (int dt = 0; dt < 8; ++dt) {
                const bf16x8 vf = *(const bf16x8*)&Vt[(dt*16 + lq) * VT_STR + kk*32 + quad*8];
                oacc[dt] = __builtin_amdgcn_mfma_f32_16x16x32_bf16(pf, vf, oacc[dt], 0, 0, 0);
            }
        }
    }

#pragma unroll
    for (int r = 0; r < 4; ++r) {
        const int iq = i0 + wave*16 + quad*4 + r;
        const float inv = 1.0f / (Zm[r] + 1e-8f * Zr[r]);
        float* op = out + ((size_t)bh * M_ + iq) * D_;
#pragma unroll
        for (int dt = 0; dt < 8; ++dt)
            op[dt*16 + lq] = oacc[dt][r] * inv;
    }
}

extern "C" void kernel_launch(void* const* d_in, const int* in_sizes, int n_in,
                              void* d_out, int out_size, void* d_ws, size_t ws_size,
                              hipStream_t stream) {
    (void)in_sizes; (void)n_in; (void)out_size;
    const float* Q       = (const float*)d_in[0];
    const float* K       = (const float*)d_in[1];
    const float* V       = (const float*)d_in[2];
    const float* hid     = (const float*)d_in[3];
    const float* counter = (const float*)d_in[4];
    const float* pe      = (const float*)d_in[5];
    const float* sw      = (const float*)d_in[6];
    const float* sb      = (const float*)d_in[7];

    float* out    = (float*)d_out;
    float* aux    = out + (size_t)BH_ * M_ * D_;
    float* r0_out = aux + B_;

    float* r0_ws = (float*)d_ws;                         // 12800 floats
    float* tmax  = r0_ws + B_ * L_;                      // 200 floats
    unsigned short* PET = (unsigned short*)(r0_ws + 13056); // 1024*128 bf16, 16B-aligned
    const bool use_pet = ws_size >= (size_t)(13056 * 4 + M_ * D_ * 2);

    span_kernel<<<(B_ * L_) / 4, 256, 0, stream>>>(hid, counter, sw, sb, r0_ws, r0_out);
    tilemax_kernel<<<B_ * NT64, 64, 0, stream>>>(r0_ws, tmax);
    aux_kernel<<<B_, 256, 0, stream>>>(r0_ws, aux);
    if (use_pet) {
        pet_kernel<<<M_ / 4, 256, 0, stream>>>(pe, PET);
        attn_kernel<<<dim3(M_ / 64, BH_), 256, 0, stream>>>(Q, K, V, PET, r0_ws, tmax, out);
    } else {
        attn_fb_kernel<<<dim3(M_ / 64, BH_), 256, 0, stream>>>(Q, K, V, pe, r0_ws, tmax, out);
    }
}

// Round 4
// 235.897 us; speedup vs baseline: 1.2384x; 1.0097x over previous
//
#include <hip/hip_runtime.h>
#include <stdint.h>

// SeqAttention: B=4,H=8,M=1024,L=3200,D=128,HID=1024, ATTN_LIM=2048, RAMP=128
#define B_   4
#define H_   8
#define BH_  32
#define M_   1024
#define L_   3200
#define D_   128
#define HID_ 1024
#define NT64 50                 /* L/64 */
#define CAUSAL_K 2175           /* max_mem - M - 1 */
#define POS_OFF  1152           /* L - 2M */
#define SCALE 0.08838834764831845f /* 1/sqrt(128) */
#define NEGV (-3.0e38f)
#define NEGH (-1.0e38f)

typedef short  bf16x8 __attribute__((ext_vector_type(8)));
typedef float  f32x4  __attribute__((ext_vector_type(4)));

__device__ __forceinline__ unsigned short f2bf(float x) {
    union { float f; uint32_t u; } v; v.f = x;
    return (unsigned short)((v.u + 0x7FFFu + ((v.u >> 16) & 1u)) >> 16);
}
__device__ __forceinline__ float bf2f(unsigned short h) {
    union { uint32_t u; float f; } v; v.u = ((uint32_t)h) << 16; return v.f;
}
// truncating pack: low16 = bf16(lo), high16 = bf16(hi) — single v_perm_b32
__device__ __forceinline__ uint32_t pack_bf2(float lo, float hi) {
    union { float f; uint32_t u; } a, b; a.f = lo; b.f = hi;
    return __builtin_amdgcn_perm(b.u, a.u, 0x07060302u);
}

// ---- DPP 16-lane reductions: pure VALU, no LDS pipe ----
template <int CTRL>
__device__ __forceinline__ float dpp_movf(float x) {
    union { float f; int i; } u; u.f = x;
    u.i = __builtin_amdgcn_update_dpp(0, u.i, CTRL, 0xF, 0xF, true);
    return u.f;
}
__device__ __forceinline__ float row_max16(float x) {
    x = fmaxf(x, dpp_movf<0xB1>(x));
    x = fmaxf(x, dpp_movf<0x4E>(x));
    x = fmaxf(x, dpp_movf<0x141>(x));
    x = fmaxf(x, dpp_movf<0x140>(x));
    return x;
}
__device__ __forceinline__ float row_sum16(float x) {
    x += dpp_movf<0xB1>(x);
    x += dpp_movf<0x4E>(x);
    x += dpp_movf<0x141>(x);
    x += dpp_movf<0x140>(x);
    return x;
}

// ---- remaining_offset[b,l] = sigmoid(dot(hid/16, w) + b)*2048 - counter ----
__global__ void span_kernel(const float* __restrict__ hid,
                            const float* __restrict__ counter,
                            const float* __restrict__ sw,
                            const float* __restrict__ sb,
                            float* __restrict__ r0_ws,
                            float* __restrict__ r0_out) {
    const int row  = blockIdx.x * 4 + (threadIdx.x >> 6);   // one wave per (b,l)
    const int lane = threadIdx.x & 63;
    const float* h = hid + (size_t)row * HID_;
    float acc = 0.f;
#pragma unroll
    for (int it = 0; it < 4; ++it) {
        const int k = it * 256 + lane * 4;
        const float4 a = *(const float4*)(h + k);
        const float4 w = *(const float4*)(sw + k);
        acc += a.x*w.x + a.y*w.y + a.z*w.z + a.w*w.w;
    }
#pragma unroll
    for (int off = 32; off; off >>= 1) acc += __shfl_down(acc, off);
    if (lane == 0) {
        const float x  = acc * (1.0f/16.0f) + sb[0];
        const float ms = 2048.0f / (1.0f + __expf(-x));
        const float r0 = ms - counter[row];
        r0_ws[row]  = r0;
        r0_out[row] = r0;
    }
}

// ---- per-(b, 64-wide l-tile) max of remaining_offset, for tile skipping ----
__global__ void tilemax_kernel(const float* __restrict__ r0_ws,
                               float* __restrict__ tmax) {
    const int t = blockIdx.x;
    const int lane = threadIdx.x;
    float v = r0_ws[t * 64 + lane];
#pragma unroll
    for (int off = 32; off; off >>= 1) v = fmaxf(v, __shfl_down(v, off));
    if (lane == 0) tmax[t] = v;
}

// ---- aux_loss: closed-form arithmetic series over m in (r, r+128) ----
__global__ void aux_kernel(const float* __restrict__ r0_ws,
                           float* __restrict__ aux_out) {
    const int b = blockIdx.x, tid = threadIdx.x;
    float s = 0.f;
    for (int l = tid; l < L_; l += 256) {
        const float r = r0_ws[b * L_ + l];
        const int fl = (int)floorf(r);
        int mlo = fl + 1;   if (mlo < 0) mlo = 0;
        int mhi = fl + 128; if (mhi > M_ - 1) mhi = M_ - 1;
        const int n = mhi - mlo + 1;
        if (n > 0) s += (float)n * r - 0.5f * (float)(mlo + mhi) * (float)n;
    }
    __shared__ float red[256];
    red[tid] = s; __syncthreads();
    for (int st = 128; st; st >>= 1) {
        if (tid < st) red[tid] += red[tid + st];
        __syncthreads();
    }
    if (tid == 0) aux_out[b] = red[0] * (1.0f/128.0f) * (1.0f/1024.0f) * 1e-6f;
}

// ---- PE (D,M) f32 -> PET (M,D) bf16, coalesced writes ----
__global__ void pet_kernel(const float* __restrict__ PE,
                           unsigned short* __restrict__ PET) {
    const int tid = threadIdx.x;
    const int c = blockIdx.x * 4 + (tid >> 6);
    const int e = tid & 63;
    const float lo = PE[(2*e)   * M_ + c];
    const float hi = PE[(2*e+1) * M_ + c];
    ((uint32_t*)PET)[c * 64 + e] = pack_bf2(lo, hi);
}

// ================= optimized flash attention =================
#define KS_STR 136   /* 128 + 8 (bf16 elems); 8*odd for b128 bank spread */
#define VT_STR 72    /* 64 + 8 */
#define PE_STR 136
#define P_STR  72
#define T_STR  72

__global__ void __launch_bounds__(256, 2)
attn_kernel(const float* __restrict__ Q, const float* __restrict__ K,
            const float* __restrict__ V, const unsigned short* __restrict__ PET,
            const float* __restrict__ r0g, const float* __restrict__ tmax,
            float* __restrict__ out) {
    __shared__ short Ks[64 * KS_STR];        // K tile [l][d]
    __shared__ short Vt[128 * VT_STR];       // V tile transposed [d][l]
    __shared__ short PEs[64 * PE_STR];       // PE^T tile [c][d]
    __shared__ short Tb[2][64 * T_STR];      // rolling Q@PE tiles [i][c] (wave-private rows)
    __shared__ short Pb[64 * P_STR];         // P tile [m][l] (wave-private rows)
    __shared__ float r0s[64];
    __shared__ float tfl[NT64];

    const int bh = blockIdx.y;
    const int b  = bh >> 3;
    const int i0 = blockIdx.x << 6;
    const int tid  = threadIdx.x;
    const int wave = tid >> 6;
    const int lane = tid & 63;
    const int lq   = lane & 15;
    const int quad = lane >> 4;
    const int lt_end = min(NT64, (int)blockIdx.x + 35);   // causal bound

    if (tid < NT64) tfl[tid] = tmax[b * NT64 + tid];
    __syncthreads();
    const float live_thresh = (float)(i0 - 128);

    auto next_live = [&](int s) {
        while (s < lt_end && !(tfl[s] > live_thresh)) ++s;
        return s;
    };

    // ---- prefetch registers (tile lt staged here before LDS write) ----
    float4 kp[8];
    float4 vpa[4], vpb[4];
    uint4  pep[4];
    float  r0p = 0.f;

    auto issue_prefetch = [&](int plt) {
        const int l0p = plt << 6;
        const float* kb = K + ((size_t)bh * L_ + l0p) * D_;
        const float* vb = V + ((size_t)bh * L_ + l0p) * D_;
#pragma unroll
        for (int it = 0; it < 8; ++it) {
            const int f = it * 256 + tid;
            kp[it] = *(const float4*)(kb + (f >> 5) * D_ + (f & 31) * 4);
        }
        const int p2 = (tid & 31) * 2;
#pragma unroll
        for (int it = 0; it < 4; ++it) {
            const int c = it * 8 + (tid >> 5);
            vpa[it] = *(const float4*)(vb + (size_t)p2 * D_ + c * 4);
            vpb[it] = *(const float4*)(vb + (size_t)(p2 + 1) * D_ + c * 4);
        }
        const int c0p = l0p - i0 - POS_OFF;
#pragma unroll
        for (int it = 0; it < 4; ++it) {
            const int f = it * 256 + tid;
            const int cg = c0p + (f >> 4);
            if ((unsigned)cg < (unsigned)M_)
                pep[it] = *(const uint4*)(PET + (size_t)cg * D_ + (f & 15) * 8);
            else { pep[it].x = 0; pep[it].y = 0; pep[it].z = 0; pep[it].w = 0; }
        }
        if (tid < 64) r0p = r0g[b * L_ + l0p + tid];
    };

    auto write_stage = [&]() {
#pragma unroll
        for (int it = 0; it < 8; ++it) {
            const int f = it * 256 + tid;
            uint2 w;
            w.x = pack_bf2(kp[it].x, kp[it].y);
            w.y = pack_bf2(kp[it].z, kp[it].w);
            *(uint2*)&Ks[(f >> 5) * KS_STR + (f & 31) * 4] = w;
        }
        const int p2 = (tid & 31) * 2;
#pragma unroll
        for (int it = 0; it < 4; ++it) {
            const int c = it * 8 + (tid >> 5);
            const float* a = (const float*)&vpa[it];
            const float* bb = (const float*)&vpb[it];
#pragma unroll
            for (int j = 0; j < 4; ++j)
                *(uint32_t*)&Vt[(c * 4 + j) * VT_STR + p2] = pack_bf2(a[j], bb[j]);
        }
#pragma unroll
        for (int it = 0; it < 4; ++it) {
            const int f = it * 256 + tid;
            *(uint4*)&PEs[(f >> 4) * PE_STR + (f & 15) * 8] = pep[it];
        }
        if (tid < 64) r0s[tid] = r0p;
    };

    // ---- Q fragments ----
    int lt = next_live(0);
    if (lt < lt_end) issue_prefetch(lt);

    bf16x8 qfrag[4];
    {
        const float* qp = Q + ((size_t)bh * M_ + (i0 + wave * 16 + lq)) * D_;
#pragma unroll
        for (int kk = 0; kk < 4; ++kk) {
            const float4 q0 = *(const float4*)(qp + kk * 32 + quad * 8);
            const float4 q1 = *(const float4*)(qp + kk * 32 + quad * 8 + 4);
            union { bf16x8 v; uint32_t u[4]; } qq;
            qq.u[0] = pack_bf2(q0.x, q0.y); qq.u[1] = pack_bf2(q0.z, q0.w);
            qq.u[2] = pack_bf2(q1.x, q1.y); qq.u[3] = pack_bf2(q1.z, q1.w);
            qfrag[kk] = qq.v;
        }
    }

    auto computeT = [&](short* tb) {
#pragma unroll
        for (int nt = 0; nt < 4; ++nt) {
            f32x4 acc = (f32x4){0.f, 0.f, 0.f, 0.f};
#pragma unroll
            for (int kk = 0; kk < 4; ++kk) {
                const bf16x8 bf = *(const bf16x8*)&PEs[(nt*16 + lq) * PE_STR + kk*32 + quad*8];
                acc = __builtin_amdgcn_mfma_f32_16x16x32_bf16(qfrag[kk], bf, acc, 0, 0, 0);
            }
#pragma unroll
            for (int r = 0; r < 4; ++r) {
                union { float f; uint32_t u; } t; t.f = acc[r];
                tb[(wave*16 + quad*4 + r) * T_STR + nt*16 + lq] = (short)(t.u >> 16);
            }
        }
    };

    f32x4 oacc[8];
#pragma unroll
    for (int d = 0; d < 8; ++d) oacc[d] = (f32x4){0.f, 0.f, 0.f, 0.f};
    float mrun[4] = {NEGV, NEGV, NEGV, NEGV};
    float Zr[4]   = {0.f, 0.f, 0.f, 0.f};
    float Zm[4]   = {0.f, 0.f, 0.f, 0.f};
    int tlo = 0, thi = 1;
    int prev_c0 = -(1 << 30);

    while (lt < lt_end) {
        const int l0 = lt << 6;
        const int c0 = l0 - i0 - POS_OFF;
        const bool need_pos = (c0 + 63 >= 0) && (c0 - 63 <= M_ - 1);
        const bool rolling  = need_pos && (prev_c0 == c0 - 64);

        __syncthreads();                       // sync0: prev LDS reads done; prefetch drained here
        write_stage();
        __syncthreads();                       // sync1: staging visible (no VMEM outstanding -> cheap)

        // issue NEXT tile's loads now — they overlap the whole compute phase
        // below and are drained at the next iteration's sync0.
        const int ltn = next_live(lt + 1);
        if (ltn < lt_end) issue_prefetch(ltn);

        // S = Q @ K^T
        f32x4 sfrag[4];
#pragma unroll
        for (int nt = 0; nt < 4; ++nt) {
            f32x4 acc = (f32x4){0.f, 0.f, 0.f, 0.f};
#pragma unroll
            for (int kk = 0; kk < 4; ++kk) {
                const bf16x8 bf = *(const bf16x8*)&Ks[(nt*16 + lq) * KS_STR + kk*32 + quad*8];
                acc = __builtin_amdgcn_mfma_f32_16x16x32_bf16(qfrag[kk], bf, acc, 0, 0, 0);
            }
            sfrag[nt] = acc;
        }

        // rel-pos T tiles (Tb rows are wave-private: no barrier needed)
        if (need_pos) {
            if (rolling) {
                const int t = tlo; tlo = thi; thi = t;
                computeT(&Tb[thi][0]);
            } else {
                tlo = 0; thi = 1;
                computeT(&Tb[1][0]);
                // restage PEs with the low tile (head/gap only, ~once per block)
                uint4 lowp[4];
#pragma unroll
                for (int it = 0; it < 4; ++it) {
                    const int f = it * 256 + tid;
                    const int cg = (c0 - 64) + (f >> 4);
                    if ((unsigned)cg < (unsigned)M_)
                        lowp[it] = *(const uint4*)(PET + (size_t)cg * D_ + (f & 15) * 8);
                    else { lowp[it].x = 0; lowp[it].y = 0; lowp[it].z = 0; lowp[it].w = 0; }
                }
                __syncthreads();               // all waves done reading PEs (T-hi)
#pragma unroll
                for (int it = 0; it < 4; ++it) {
                    const int f = it * 256 + tid;
                    *(uint4*)&PEs[(f >> 4) * PE_STR + (f & 15) * 8] = lowp[it];
                }
                __syncthreads();
                computeT(&Tb[0][0]);
            }
            prev_c0 = c0;
        } else {
            prev_c0 = -(1 << 30);
        }

        // masked scores (C-layout: row = quad*4+r, col = nt*16+lq)
        float rv[4];
#pragma unroll
        for (int nt = 0; nt < 4; ++nt) rv[nt] = r0s[nt*16 + lq];

        float sv[4][4], em[4][4];
#pragma unroll
        for (int r = 0; r < 4; ++r) {
            const int iq = i0 + wave*16 + quad*4 + r;
            const float fiq = (float)iq;
#pragma unroll
            for (int nt = 0; nt < 4; ++nt) {
                const int l = l0 + nt*16 + lq;
                float s = sfrag[nt][r];
                const int c = l - iq - POS_OFF;
                if (need_pos && (unsigned)c < (unsigned)M_) {
                    const int cb = c - (c0 - 64);          // in [1,127]
                    const short* tbp = (cb & 64) ? &Tb[thi][0] : &Tb[tlo][0];
                    s += bf2f((unsigned short)tbp[(wave*16 + quad*4 + r) * T_STR + (cb & 63)]);
                }
                const float e = fminf(fmaxf((rv[nt] - fiq) * 0.0078125f + 1.0f, 0.f), 1.f);
                em[r][nt] = e;
                const bool live = (l <= iq + CAUSAL_K) && (e > 0.f);
                sv[r][nt] = live ? s * SCALE : NEGV;
            }
        }

        // online softmax + P (= e * emask) to LDS — DPP reductions
#pragma unroll
        for (int r = 0; r < 4; ++r) {
            float v = fmaxf(fmaxf(sv[r][0], sv[r][1]), fmaxf(sv[r][2], sv[r][3]));
            v = row_max16(v);
            const float nm = fmaxf(mrun[r], v);
            float alpha = 1.f, psum = 0.f, pmsum = 0.f, pmv[4];
            if (nm > NEGH) {
                alpha = (mrun[r] > NEGH) ? __expf(mrun[r] - nm) : 0.f;
#pragma unroll
                for (int nt = 0; nt < 4; ++nt) {
                    const float p = __expf(sv[r][nt] - nm);   // dead -> 0
                    const float pm = p * em[r][nt];
                    psum += p; pmsum += pm; pmv[nt] = pm;
                }
            } else {
                pmv[0] = pmv[1] = pmv[2] = pmv[3] = 0.f;
            }
            psum  = row_sum16(psum);
            pmsum = row_sum16(pmsum);
            mrun[r] = nm;
            Zr[r] = Zr[r] * alpha + psum;
            Zm[r] = Zm[r] * alpha + pmsum;
#pragma unroll
            for (int d = 0; d < 8; ++d) oacc[d][r] *= alpha;
#pragma unroll
            for (int nt = 0; nt < 4; ++nt) {
                union { float f; uint32_t u; } t; t.f = pmv[nt];
                Pb[(wave*16 + quad*4 + r) * P_STR + nt*16 + lq] = (short)(t.u >> 16);
            }
        }
        // no barrier: Pb rows are wave-private (writer rows wave*16+quad*4+r,
        // reader rows wave*16+lq are the same 16-row strip)

        // O += P @ V
#pragma unroll
        for (int kk = 0; kk < 2; ++kk) {
            const bf16x8 pf = *(const bf16x8*)&Pb[(wave*16 + lq) * P_STR + kk*32 + quad*8];
#pragma unroll
            for (int dt = 0; dt < 8; ++dt) {
                const bf16x8 vf = *(const bf16x8*)&Vt[(dt*16 + lq) * VT_STR + kk*32 + quad*8];
                oacc[dt] = __builtin_amdgcn_mfma_f32_16x16x32_bf16(pf, vf, oacc[dt], 0, 0, 0);
            }
        }
        lt = ltn;
    }

    // epilogue: out = O / (Zm + 1e-8 * Z)
#pragma unroll
    for (int r = 0; r < 4; ++r) {
        const int iq = i0 + wave*16 + quad*4 + r;
        const float inv = 1.0f / (Zm[r] + 1e-8f * Zr[r]);
        float* op = out + ((size_t)bh * M_ + iq) * D_;
#pragma unroll
        for (int dt = 0; dt < 8; ++dt)
            op[dt*16 + lq] = oacc[dt][r] * inv;
    }
}

// ================= fallback (only if ws too small for PET) =================
__global__ void __launch_bounds__(256, 2)
attn_fb_kernel(const float* __restrict__ Q, const float* __restrict__ K,
               const float* __restrict__ V, const float* __restrict__ PE,
               const float* __restrict__ r0g, const float* __restrict__ tmax,
               float* __restrict__ out) {
    __shared__ short Ks[64 * KS_STR];
    __shared__ short Vt[128 * VT_STR];
    __shared__ short PEP[64 * PE_STR];
    __shared__ short Tb[2][64 * T_STR];
    __shared__ float r0s[64];

    const int bh = blockIdx.y;
    const int b  = bh >> 3;
    const int i0 = blockIdx.x << 6;
    const int tid  = threadIdx.x;
    const int wave = tid >> 6;
    const int lane = tid & 63;
    const int lq   = lane & 15;
    const int quad = lane >> 4;

    bf16x8 qfrag[4];
    {
        const float* qp = Q + ((size_t)bh * M_ + (i0 + wave * 16 + lq)) * D_;
#pragma unroll
        for (int kk = 0; kk < 4; ++kk) {
            const float* p = qp + kk * 32 + quad * 8;
            bf16x8 f;
#pragma unroll
            for (int j = 0; j < 8; ++j) f[j] = (short)f2bf(p[j]);
            qfrag[kk] = f;
        }
    }

    f32x4 oacc[8];
#pragma unroll
    for (int d = 0; d < 8; ++d) oacc[d] = (f32x4){0.f, 0.f, 0.f, 0.f};
    float mrun[4] = {NEGV, NEGV, NEGV, NEGV};
    float Zr[4]   = {0.f, 0.f, 0.f, 0.f};
    float Zm[4]   = {0.f, 0.f, 0.f, 0.f};

    int tlo = 0, thi = 1;
    int prev_c0 = -100000;

    auto stagePE = [&](int cbase) {
#pragma unroll
        for (int it = 0; it < 8; ++it) {
            const int f4 = it * 256 + tid;
            const int d  = f4 >> 4;
            const int cl = (f4 & 15) << 2;
#pragma unroll
            for (int j = 0; j < 4; ++j) {
                const int cg = cbase + cl + j;
                const float v = (cg >= 0 && cg < M_) ? PE[d * M_ + cg] : 0.f;
                PEP[(cl + j) * PE_STR + d] = (short)f2bf(v);
            }
        }
    };
    auto computeT = [&](short* tb) {
#pragma unroll
        for (int nt = 0; nt < 4; ++nt) {
            f32x4 acc = (f32x4){0.f, 0.f, 0.f, 0.f};
#pragma unroll
            for (int kk = 0; kk < 4; ++kk) {
                const bf16x8 bf = *(const bf16x8*)&PEP[(nt*16 + lq) * PE_STR + kk*32 + quad*8];
                acc = __builtin_amdgcn_mfma_f32_16x16x32_bf16(qfrag[kk], bf, acc, 0, 0, 0);
            }
#pragma unroll
            for (int r = 0; r < 4; ++r)
                tb[(wave*16 + quad*4 + r) * T_STR + nt*16 + lq] = (short)f2bf(acc[r]);
        }
    };

    const int lt_end = min(NT64, (int)blockIdx.x + 35);
    for (int lt = 0; lt < lt_end; ++lt) {
        const int l0 = lt << 6;
        if (!(tmax[b * NT64 + lt] > (float)(i0 - 128))) continue;

        __syncthreads();
        {
            const float* kbase = K + ((size_t)bh * L_ + l0) * D_;
            const float* vbase = V + ((size_t)bh * L_ + l0) * D_;
#pragma unroll
            for (int it = 0; it < 8; ++it) {
                const int f4 = it * 256 + tid;
                const int row = f4 >> 5;
                const int ds  = (f4 & 31) << 2;
                const float4 kv = *(const float4*)(kbase + row * D_ + ds);
                uint2 pk;
                pk.x = (uint32_t)f2bf(kv.x) | ((uint32_t)f2bf(kv.y) << 16);
                pk.y = (uint32_t)f2bf(kv.z) | ((uint32_t)f2bf(kv.w) << 16);
                *(uint2*)&Ks[row * KS_STR + ds] = pk;
                const float4 vv = *(const float4*)(vbase + row * D_ + ds);
                Vt[(ds+0) * VT_STR + row] = (short)f2bf(vv.x);
                Vt[(ds+1) * VT_STR + row] = (short)f2bf(vv.y);
                Vt[(ds+2) * VT_STR + row] = (short)f2bf(vv.z);
                Vt[(ds+3) * VT_STR + row] = (short)f2bf(vv.w);
            }
            if (tid < 64) r0s[tid] = r0g[b * L_ + l0 + tid];
        }

        const int c0 = l0 - i0 - POS_OFF;
        const bool need_pos = (c0 + 63 >= 0) && (c0 - 63 <= M_ - 1);
        if (need_pos) {
            if (prev_c0 == c0 - 64) {
                const int t = tlo; tlo = thi; thi = t;
                stagePE(c0);
                __syncthreads();
                computeT(&Tb[thi][0]);
            } else {
                stagePE(c0 - 64);
                __syncthreads();
                computeT(&Tb[0][0]);
                __syncthreads();
                stagePE(c0);
                __syncthreads();
                computeT(&Tb[1][0]);
                tlo = 0; thi = 1;
            }
            prev_c0 = c0;
        } else {
            __syncthreads();
        }

        f32x4 sfrag[4];
#pragma unroll
        for (int nt = 0; nt < 4; ++nt) {
            f32x4 acc = (f32x4){0.f, 0.f, 0.f, 0.f};
#pragma unroll
            for (int kk = 0; kk < 4; ++kk) {
                const bf16x8 bf = *(const bf16x8*)&Ks[(nt*16 + lq) * KS_STR + kk*32 + quad*8];
                acc = __builtin_amdgcn_mfma_f32_16x16x32_bf16(qfrag[kk], bf, acc, 0, 0, 0);
            }
            sfrag[nt] = acc;
        }
        __syncthreads();

        float sv[4][4];
#pragma unroll
        for (int r = 0; r < 4; ++r) {
            const int iq = i0 + wave*16 + quad*4 + r;
#pragma unroll
            for (int nt = 0; nt < 4; ++nt) {
                const int l = l0 + nt*16 + lq;
                float s = sfrag[nt][r];
                const int c = l - iq - POS_OFF;
                if (c >= 0 && c < M_) {
                    const int cb = c - (c0 - 64);
                    const short* tbp = (cb & 64) ? &Tb[thi][0] : &Tb[tlo][0];
                    s += bf2f((unsigned short)tbp[(wave*16 + quad*4 + r) * T_STR + (cb & 63)]);
                }
                const float e = fminf(fmaxf((r0s[nt*16 + lq] - (float)iq) * 0.0078125f + 1.0f, 0.f), 1.f);
                const bool live = (l <= iq + CAUSAL_K) && (e > 0.f);
                sv[r][nt] = live ? s * SCALE : NEGV;
            }
        }

#pragma unroll
        for (int r = 0; r < 4; ++r) {
            float v = fmaxf(fmaxf(sv[r][0], sv[r][1]), fmaxf(sv[r][2], sv[r][3]));
            v = row_max16(v);
            const float nm = fmaxf(mrun[r], v);
            float alpha, pmv[4];
            float psum = 0.f, pmsum = 0.f;
            if (nm > NEGH) {
                alpha = (mrun[r] > NEGH) ? __expf(mrun[r] - nm) : 0.f;
                const int iq = i0 + wave*16 + quad*4 + r;
#pragma unroll
                for (int nt = 0; nt < 4; ++nt) {
                    const float p = __expf(sv[r][nt] - nm);
                    const float e = fminf(fmaxf((r0s[nt*16 + lq] - (float)iq) * 0.0078125f + 1.0f, 0.f), 1.f);
                    const float pm = p * e;
                    psum += p; pmsum += pm; pmv[nt] = pm;
                }
            } else {
                alpha = 1.f;
                pmv[0] = pmv[1] = pmv[2] = pmv[3] = 0.f;
            }
            psum  = row_sum16(psum);
            pmsum = row_sum16(pmsum);
            mrun[r] = nm;
            Zr[r] = Zr[r] * alpha + psum;
            Zm[r] = Zm[r] * alpha + pmsum;
#pragma unroll
            for (int d = 0; d < 8; ++d) oacc[d][r] *= alpha;
#pragma unroll
            for (int nt = 0; nt < 4; ++nt)
                PEP[(wave*16 + quad*4 + r) * P_STR + nt*16 + lq] = (short)f2bf(pmv[nt]);
        }
        __syncthreads();

#pragma unroll
        for (int kk = 0; kk < 2; ++kk) {
            const bf16x8 pf = *(const bf16x8*)&PEP[(wave*16 + lq) * P_STR + kk*32 + quad*8];
#pragma unroll
            for (int dt = 0; dt < 8; ++dt) {
                const bf16x8 vf = *(const bf16x8*)&Vt[(dt*16 + lq) * VT_STR + kk*32 + quad*8];
                oacc[dt] = __builtin_amdgcn_mfma_f32_16x16x32_bf16(pf, vf, oacc[dt], 0, 0, 0);
            }
        }
    }

#pragma unroll
    for (int r = 0; r < 4; ++r) {
        const int iq = i0 + wave*16 + quad*4 + r;
        const float inv = 1.0f / (Zm[r] + 1e-8f * Zr[r]);
        float* op = out + ((size_t)bh * M_ + iq) * D_;
#pragma unroll
        for (int dt = 0; dt < 8; ++dt)
            op[dt*16 + lq] = oacc[dt][r] * inv;
    }
}

extern "C" void kernel_launch(void* const* d_in, const int* in_sizes, int n_in,
                              void* d_out, int out_size, void* d_ws, size_t ws_size,
                              hipStream_t stream) {
    (void)in_sizes; (void)n_in; (void)out_size;
    const float* Q       = (const float*)d_in[0];
    const float* K       = (const float*)d_in[1];
    const float* V       = (const float*)d_in[2];
    const float* hid     = (const float*)d_in[3];
    const float* counter = (const float*)d_in[4];
    const float* pe      = (const float*)d_in[5];
    const float* sw      = (const float*)d_in[6];
    const float* sb      = (const float*)d_in[7];

    float* out    = (float*)d_out;
    float* aux    = out + (size_t)BH_ * M_ * D_;
    float* r0_out = aux + B_;

    float* r0_ws = (float*)d_ws;                         // 12800 floats
    float* tmax  = r0_ws + B_ * L_;                      // 200 floats
    unsigned short* PET = (unsigned short*)(r0_ws + 13056); // 1024*128 bf16, 16B-aligned
    const bool use_pet = ws_size >= (size_t)(13056 * 4 + M_ * D_ * 2);

    span_kernel<<<(B_ * L_) / 4, 256, 0, stream>>>(hid, counter, sw, sb, r0_ws, r0_out);
    tilemax_kernel<<<B_ * NT64, 64, 0, stream>>>(r0_ws, tmax);
    if (use_pet) {
        pet_kernel<<<M_ / 4, 256, 0, stream>>>(pe, PET);
        attn_kernel<<<dim3(M_ / 64, BH_), 256, 0, stream>>>(Q, K, V, PET, r0_ws, tmax, out);
    } else {
        attn_fb_kernel<<<dim3(M_ / 64, BH_), 256, 0, stream>>>(Q, K, V, pe, r0_ws, tmax, out);
    }
    // aux only depends on r0_ws; run it after attn so it doesn't delay it
    aux_kernel<<<B_, 256, 0, stream>>>(r0_ws, aux);
}